// Round 5
// baseline (339.296 us; speedup 1.0000x reference)
//
#include <hip/hip_runtime.h>
#include <math.h>

// ---------------------------------------------------------------------------
// ConvAttention (B=32, T1=1600, T2=400, n_mel=80, n_text=512, n_att=80)
// Round 5: conv_mfma K-loop ported to m97 structure:
//   global_load_lds(16B) staging into linear [128][32] LDS tiles, 2-barrier,
//   two-pass epilogue transpose (LDS 35.8 -> 17.4 KB).
// ---------------------------------------------------------------------------

typedef __attribute__((ext_vector_type(8))) short bf16x8;
typedef __attribute__((ext_vector_type(4))) float f32x4;

static __device__ __forceinline__ unsigned short f2bf(float f) {
    union { float f; unsigned u; } v; v.f = f;
    unsigned r = v.u + 0x7FFF + ((v.u >> 16) & 1);
    return (unsigned short)(r >> 16);
}
static __device__ __forceinline__ float bf2f(unsigned short h) {
    union { unsigned u; float f; } v; v.u = ((unsigned)h) << 16;
    return v.f;
}

#define GLOAD16(g, s) __builtin_amdgcn_global_load_lds( \
    (const __attribute__((address_space(1))) void*)(g), \
    (__attribute__((address_space(3))) void*)(s), 16, 0, 0)

// ---------------- weight converter ----------------
__global__ __launch_bounds__(256) void convert_wgt(
    const float* __restrict__ w, unsigned short* __restrict__ Wbf,
    int Cout, int Cin, int KTAP, int CoutAlloc, int CinPad)
{
    int idx = blockIdx.x * 256 + threadIdx.x;
    int total = KTAP * CoutAlloc * CinPad;
    if (idx >= total) return;
    int d   = idx / (CoutAlloc * CinPad);
    int rem = idx - d * (CoutAlloc * CinPad);
    int co  = rem / CinPad;
    int ci  = rem - co * CinPad;
    float v = 0.f;
    if (co < Cout && ci < Cin)
        v = w[((size_t)co * Cin + ci) * KTAP + d];
    Wbf[idx] = f2bf(v);
}

// ---------------- input converter (transpose + pad) ----------------
__global__ __launch_bounds__(256) void convert_inp(
    const float* __restrict__ in, unsigned short* __restrict__ Xt,
    int C, int CinPad, int T, int Trow, int PAD)
{
    __shared__ float s[32][33];
    int b = blockIdx.z, ci0 = blockIdx.y * 32, tr0 = blockIdx.x * 32;
    int tx = threadIdx.x & 31, ty = threadIdx.x >> 5;
#pragma unroll
    for (int i = 0; i < 4; i++) {
        int c = ci0 + ty + 8 * i;
        int t_in = tr0 + tx - PAD;
        float v = (c < C && t_in >= 0 && t_in < T)
                    ? in[((size_t)b * C + c) * T + t_in] : 0.f;
        s[ty + 8 * i][tx] = v;
    }
    __syncthreads();
#pragma unroll
    for (int i = 0; i < 4; i++) {
        int tr = tr0 + ty + 8 * i;
        if (tr < Trow)
            Xt[((size_t)b * Trow + tr) * CinPad + ci0 + tx] = f2bf(s[tx][ty + 8 * i]);
    }
}

__global__ __launch_bounds__(256) void zero_tail_k(unsigned short* __restrict__ Xk)
{
    int i = blockIdx.x * 256 + threadIdx.x;
    if (i < 4 * 512) Xk[(size_t)12928 * 512 + i] = 0;
}
__global__ __launch_bounds__(256) void zero_tail_q(unsigned short* __restrict__ Xq)
{
    int i = blockIdx.x * 256 + threadIdx.x;
    if (i < 4 * 96) Xq[(size_t)51328 * 96 + i] = 0;
}

// ---------------- generic conv-as-GEMM, bf16 MFMA, async staging ----------
// A = Wbf [KTAP][CoutAlloc][CinPad], B = Xt rows (n + d), K = KTAP*CinPad.
// out bf16 [(b*Tout+t)*OutStride + co], zero-fill co in [Cout, OutStride).
template <int KTAP, bool RELU>
__global__ __launch_bounds__(256) void conv_mfma(
    const unsigned short* __restrict__ Wbf,
    const unsigned short* __restrict__ Xt,
    const float* __restrict__ bias,
    unsigned short* __restrict__ out,
    int CinPad, int CoutAlloc, int Cout, int Trow, int Tout, int OutStride)
{
    constexpr int TRW = 136; // transpose row stride (16B aligned)
    __shared__ unsigned short lds[64 * TRW]; // 8704 shorts = 17.4 KB
    unsigned short* Al = lds;          // [128][32] linear
    unsigned short* Bl = lds + 4096;   // [128][32] linear

    const int tid  = threadIdx.x;
    const int lane = tid & 63;
    const int wid  = tid >> 6;
    const int wm   = wid >> 1;
    const int wn   = wid & 1;
    const int co0  = blockIdx.y * 128;
    const int n0   = blockIdx.x * 128;

    const int srow = (lane >> 2);        // 0..15 staging sub-row
    const int scol = (lane & 3) * 8;     // ci sub-offset
    const int fr   = lane & 15;
    const int ko   = (lane >> 4) * 8;

    const int nKc   = CinPad >> 5;
    const int nIter = KTAP * nKc;

    f32x4 acc[4][4] = {};

    int cc = 0, d = 0;
    for (int kk = 0; kk < nIter; kk++) {
        int ci0 = cc * 32;
        const unsigned short* asrc =
            Wbf + ((size_t)d * CoutAlloc + co0 + wid * 32 + srow) * CinPad + ci0 + scol;
        const unsigned short* bsrc =
            Xt + ((size_t)(n0 + d) + wid * 32 + srow) * CinPad + ci0 + scol;

        __syncthreads(); // previous tile's ds_reads complete
        GLOAD16(asrc,                    &Al[wid * 1024]);
        GLOAD16(asrc + (size_t)16 * CinPad, &Al[wid * 1024 + 512]);
        GLOAD16(bsrc,                    &Bl[wid * 1024]);
        GLOAD16(bsrc + (size_t)16 * CinPad, &Bl[wid * 1024 + 512]);
        __syncthreads(); // vmcnt(0) drained before barrier -> tile visible

        bf16x8 af[4], bfr[4];
#pragma unroll
        for (int mi = 0; mi < 4; mi++)
            af[mi] = *(const bf16x8*)&Al[(wm * 64 + mi * 16 + fr) * 32 + ko];
#pragma unroll
        for (int ni = 0; ni < 4; ni++)
            bfr[ni] = *(const bf16x8*)&Bl[(wn * 64 + ni * 16 + fr) * 32 + ko];
#pragma unroll
        for (int mi = 0; mi < 4; mi++)
#pragma unroll
            for (int ni = 0; ni < 4; ni++)
                acc[mi][ni] = __builtin_amdgcn_mfma_f32_16x16x32_bf16(
                    af[mi], bfr[ni], acc[mi][ni], 0, 0, 0);

        cc++; if (cc == nKc) { cc = 0; d++; }
    }

    // two-pass LDS-transpose epilogue -> contiguous bf16 row writes
    int cw = OutStride - co0; if (cw > 128) cw = 128;
#pragma unroll
    for (int p = 0; p < 2; p++) {
        __syncthreads();
        if (wn == p) {
#pragma unroll
            for (int mi = 0; mi < 4; mi++) {
                int col = wm * 64 + mi * 16 + (lane >> 4) * 4;
#pragma unroll
                for (int ni = 0; ni < 4; ni++) {
                    int row = ni * 16 + fr; // 0..63 within this pass
                    unsigned short pk[4];
#pragma unroll
                    for (int r = 0; r < 4; r++) {
                        int co = co0 + col + r;
                        float v = 0.f;
                        if (co < Cout) {
                            v = acc[mi][ni][r] + bias[co];
                            if (RELU) v = fmaxf(v, 0.f);
                        }
                        pk[r] = f2bf(v);
                    }
                    *(unsigned long long*)&lds[row * TRW + col] = *(unsigned long long*)pk;
                }
            }
        }
        __syncthreads();
        int rr = tid >> 2;            // 0..63
        int c0 = (tid & 3) * 32;      // 32-elem chunk
        int n  = n0 + p * 64 + rr;
        int b  = n / Trow;
        int t  = n - b * Trow;
        if (t < Tout) {
            unsigned short* dst = out + ((size_t)b * Tout + t) * OutStride + co0;
#pragma unroll
            for (int c = c0; c < c0 + 32; c += 8)
                if (c < cw)
                    *(bf16x8*)&dst[c] = *(const bf16x8*)&lds[rr * TRW + c];
        }
    }
}

// ---------------- k2 from bf16 Kt ----------------
__global__ __launch_bounds__(256) void k2_kernel(
    const unsigned short* __restrict__ Kt, float* __restrict__ k2s)
{
    int lane = threadIdx.x & 63, w = threadIdx.x >> 6;
    int row = blockIdx.x * 64 + w * 16 + (lane >> 2);
    int c0 = (lane & 3) * 24;
    const unsigned short* p = Kt + (size_t)row * 96 + c0;
    float s = 0.f;
#pragma unroll
    for (int i = 0; i < 3; i++) {
        bf16x8 v = *(const bf16x8*)&p[i * 8];
#pragma unroll
        for (int e = 0; e < 8; e++) {
            float f = bf2f((unsigned short)v[e]);
            s = fmaf(f, f, s);
        }
    }
    s += __shfl_xor(s, 1);
    s += __shfl_xor(s, 2);
    if ((lane & 3) == 0) k2s[row] = s;
}

// ---------------- fused MFMA-QK + softmax/logprob ----------------
#define NS 7
#define SCW 404
__global__ __launch_bounds__(512) void attn_v2(
    const unsigned short* __restrict__ Kt,   // [32*400][96] bf16
    const unsigned short* __restrict__ Qt,   // [32*1600][96] bf16
    const float* __restrict__ k2s,           // [32*400]
    const float* __restrict__ prior, const int* __restrict__ mask,
    float* __restrict__ out_attn, float* __restrict__ out_lp)
{
    const int T1 = 1600, T2 = 400;
    __shared__ float Sc[32 * SCW];

    const int tid  = threadIdx.x;
    const int lane = tid & 63;
    const int wid  = tid >> 6;
    const int b    = blockIdx.y;
    const int t0   = blockIdx.x * 32;
    const int fr   = lane & 15;
    const int ko   = (lane >> 4) * 8;

    bf16x8 qf[2][3];
#pragma unroll
    for (int ts = 0; ts < 2; ts++)
#pragma unroll
        for (int kk = 0; kk < 3; kk++)
            qf[ts][kk] = *(const bf16x8*)&Qt[((size_t)b * T1 + t0 + ts * 16 + fr) * 96 + kk * 32 + ko];

    for (int st = wid; st < 25; st += 8) {
        f32x4 acc0 = {}, acc1 = {};
#pragma unroll
        for (int kk = 0; kk < 3; kk++) {
            bf16x8 kf = *(const bf16x8*)&Kt[((size_t)b * T2 + st * 16 + fr) * 96 + kk * 32 + ko];
            acc0 = __builtin_amdgcn_mfma_f32_16x16x32_bf16(kf, qf[0][kk], acc0, 0, 0, 0);
            acc1 = __builtin_amdgcn_mfma_f32_16x16x32_bf16(kf, qf[1][kk], acc1, 0, 0, 0);
        }
        int sbase = st * 16 + (lane >> 4) * 4;
        float4 kv = *(const float4*)&k2s[b * T2 + sbase];
        float4 w0, w1;
        w0.x = fmaf(1e-3f, acc0[0], -5e-4f * kv.x);
        w0.y = fmaf(1e-3f, acc0[1], -5e-4f * kv.y);
        w0.z = fmaf(1e-3f, acc0[2], -5e-4f * kv.z);
        w0.w = fmaf(1e-3f, acc0[3], -5e-4f * kv.w);
        w1.x = fmaf(1e-3f, acc1[0], -5e-4f * kv.x);
        w1.y = fmaf(1e-3f, acc1[1], -5e-4f * kv.y);
        w1.z = fmaf(1e-3f, acc1[2], -5e-4f * kv.z);
        w1.w = fmaf(1e-3f, acc1[3], -5e-4f * kv.w);
        *(float4*)&Sc[fr * SCW + sbase]        = w0;
        *(float4*)&Sc[(16 + fr) * SCW + sbase] = w1;
    }

    int mk[NS];
#pragma unroll
    for (int j = 0; j < NS; j++) {
        int s = lane + 64 * j;
        mk[j] = (s < T2) ? mask[b * T2 + s] : 1;
    }

    __syncthreads();

    for (int r = 0; r < 4; r++) {
        int tloc = wid * 4 + r;
        int t = t0 + tloc;

        float scr[NS];
        float m = -INFINITY;
#pragma unroll
        for (int j = 0; j < NS; j++) {
            int s = lane + 64 * j;
            if (s < T2) {
                scr[j] = Sc[tloc * SCW + s];
                m = fmaxf(m, scr[j]);
            } else {
                scr[j] = -INFINITY;
            }
        }
#pragma unroll
        for (int o = 32; o >= 1; o >>= 1) m = fmaxf(m, __shfl_xor(m, o));
        float sum = 0.f;
#pragma unroll
        for (int j = 0; j < NS; j++) {
            int s = lane + 64 * j;
            if (s < T2) sum += __expf(scr[j] - m);
        }
#pragma unroll
        for (int o = 32; o >= 1; o >>= 1) sum += __shfl_xor(sum, o);
        float lse = m + __logf(sum);

        const float* pr = prior + ((size_t)b * T1 + t) * T2;
        float* lpout = out_lp + ((size_t)b * T1 + t) * T2;
        float* atout = out_attn + ((size_t)b * T1 + t) * T2;

        float val[NS];
        float m2 = -INFINITY;
#pragma unroll
        for (int j = 0; j < NS; j++) {
            int s = lane + 64 * j;
            if (s < T2) {
                float lp = scr[j] - lse + __logf(pr[s] + 1e-8f);
                lpout[s] = lp;
                val[j] = mk[j] ? -INFINITY : lp;
                m2 = fmaxf(m2, val[j]);
            } else {
                val[j] = -INFINITY;
            }
        }
#pragma unroll
        for (int o = 32; o >= 1; o >>= 1) m2 = fmaxf(m2, __shfl_xor(m2, o));
        float ex[NS];
        float sum2 = 0.f;
#pragma unroll
        for (int j = 0; j < NS; j++) { ex[j] = __expf(val[j] - m2); sum2 += ex[j]; }
#pragma unroll
        for (int o = 32; o >= 1; o >>= 1) sum2 += __shfl_xor(sum2, o);
        float inv = 1.f / sum2;
#pragma unroll
        for (int j = 0; j < NS; j++) {
            int s = lane + 64 * j;
            if (s < T2) atout[s] = ex[j] * inv;
        }
    }
}

// ---------------------------------------------------------------------------
extern "C" void kernel_launch(void* const* d_in, const int* in_sizes, int n_in,
                              void* d_out, int out_size, void* d_ws, size_t ws_size,
                              hipStream_t stream)
{
    (void)in_sizes; (void)n_in; (void)out_size; (void)ws_size;

    const float* queries = (const float*)d_in[0];
    const float* keys    = (const float*)d_in[1];
    const float* prior   = (const float*)d_in[2];
    const int*   mask    = (const int*)d_in[3];
    const float* kw1     = (const float*)d_in[4];
    const float* kb1     = (const float*)d_in[5];
    const float* kw2     = (const float*)d_in[6];
    const float* kb2     = (const float*)d_in[7];
    const float* qw1     = (const float*)d_in[8];
    const float* qb1     = (const float*)d_in[9];
    const float* qw2     = (const float*)d_in[10];
    const float* qb2     = (const float*)d_in[11];
    const float* qw3     = (const float*)d_in[12];
    const float* qb3     = (const float*)d_in[13];

    float* ws = (float*)d_ws;
    unsigned short* K1t = (unsigned short*)(ws);                 // [12800][1024] bf16
    unsigned short* Q1t = (unsigned short*)(ws);                 // [51200][160] bf16 (reuse)
    unsigned short* Xk  = (unsigned short*)(ws + 6553600);       // [12932][512] bf16
    unsigned short* Xq  = (unsigned short*)(ws + 6553600);       // [51332][96] bf16 (reuse)
    unsigned short* Qt  = (unsigned short*)(ws + 6553600);       // [51200][96] bf16 (reuse)
    unsigned short* Kt  = (unsigned short*)(ws + 9864192);       // [12800][96] bf16
    unsigned short* Q2t = (unsigned short*)(ws + 10479360);      // [51200][96] bf16
    unsigned short* Wk1 = (unsigned short*)(ws + 12936960);      // 3*1024*512
    unsigned short* Wk2 = (unsigned short*)(ws + 13723392);      // 128*1024
    unsigned short* Wq1 = (unsigned short*)(ws + 13788928);      // 3*256*96
    unsigned short* Wq2 = (unsigned short*)(ws + 13825792);      // 128*160
    unsigned short* Wq3 = (unsigned short*)(ws + 13836032);      // 128*96
    float*          k2s = ws + 13842176;                         // 12800 f32

    float* out_attn = (float*)d_out;
    float* out_lp   = out_attn + (size_t)32 * 1600 * 400;

    dim3 blk(256);

    // weight conversions
    convert_wgt<<<(3 * 1024 * 512 + 255) / 256, blk, 0, stream>>>(kw1, Wk1, 1024, 512, 3, 1024, 512);
    convert_wgt<<<(1 * 128 * 1024 + 255) / 256, blk, 0, stream>>>(kw2, Wk2, 80, 1024, 1, 128, 1024);
    convert_wgt<<<(3 * 256 * 96   + 255) / 256, blk, 0, stream>>>(qw1, Wq1, 160, 80, 3, 256, 96);
    convert_wgt<<<(1 * 128 * 160  + 255) / 256, blk, 0, stream>>>(qw2, Wq2, 80, 160, 1, 128, 160);
    convert_wgt<<<(1 * 128 * 96   + 255) / 256, blk, 0, stream>>>(qw3, Wq3, 80, 80, 1, 128, 96);

    // key path
    convert_inp<<<dim3(13, 16, 32), blk, 0, stream>>>(keys, Xk, 512, 512, 400, 404, 1);
    zero_tail_k<<<8, blk, 0, stream>>>(Xk);
    conv_mfma<3, true ><<<dim3(101, 8), blk, 0, stream>>>(Wk1, Xk, kb1, K1t, 512, 1024, 1024, 404, 400, 1024);
    conv_mfma<1, false><<<dim3(100, 1), blk, 0, stream>>>(Wk2, K1t, kb2, Kt, 1024, 128, 80, 400, 400, 96);
    k2_kernel<<<200, blk, 0, stream>>>(Kt, k2s);

    // query path (Xq over dead Xk; Q1t over dead K1t; Qt over dead Xq)
    convert_inp<<<dim3(51, 3, 32), blk, 0, stream>>>(queries, Xq, 80, 96, 1600, 1604, 1);
    zero_tail_q<<<8, blk, 0, stream>>>(Xq);
    conv_mfma<3, true ><<<dim3(401, 2), blk, 0, stream>>>(Wq1, Xq, qb1, Q1t, 96, 256, 160, 1604, 1600, 160);
    conv_mfma<1, true ><<<dim3(400, 1), blk, 0, stream>>>(Wq2, Q1t, qb2, Q2t, 160, 128, 80, 1600, 1600, 96);
    conv_mfma<1, false><<<dim3(400, 1), blk, 0, stream>>>(Wq3, Q2t, qb3, Qt, 96, 128, 80, 1600, 1600, 96);

    // fused attention + softmaxes
    attn_v2<<<dim3(50, 32), dim3(512), 0, stream>>>(Kt, Qt, k2s, prior, mask, out_attn, out_lp);
}

// Round 6
// 321.444 us; speedup vs baseline: 1.0555x; 1.0555x over previous
//
#include <hip/hip_runtime.h>
#include <math.h>

// ---------------------------------------------------------------------------
// ConvAttention (B=32, T1=1600, T2=400, n_mel=80, n_text=512, n_att=80)
// Round 6: conv_mfma with T3-minimum double-buffered global_load_lds
//   (stage k+1 into buf^1, compute k from buf, ONE barrier/iter) +
//   T1 XCD-bijective swizzle (m204) with co-fastest work order for L2 reuse.
// ---------------------------------------------------------------------------

typedef __attribute__((ext_vector_type(8))) short bf16x8;
typedef __attribute__((ext_vector_type(4))) float f32x4;

static __device__ __forceinline__ unsigned short f2bf(float f) {
    union { float f; unsigned u; } v; v.f = f;
    unsigned r = v.u + 0x7FFF + ((v.u >> 16) & 1);
    return (unsigned short)(r >> 16);
}
static __device__ __forceinline__ float bf2f(unsigned short h) {
    union { unsigned u; float f; } v; v.u = ((unsigned)h) << 16;
    return v.f;
}

#define GLOAD16(g, s) __builtin_amdgcn_global_load_lds( \
    (const __attribute__((address_space(1))) void*)(g), \
    (__attribute__((address_space(3))) void*)(s), 16, 0, 0)

// ---------------- weight converter ----------------
__global__ __launch_bounds__(256) void convert_wgt(
    const float* __restrict__ w, unsigned short* __restrict__ Wbf,
    int Cout, int Cin, int KTAP, int CoutAlloc, int CinPad)
{
    int idx = blockIdx.x * 256 + threadIdx.x;
    int total = KTAP * CoutAlloc * CinPad;
    if (idx >= total) return;
    int d   = idx / (CoutAlloc * CinPad);
    int rem = idx - d * (CoutAlloc * CinPad);
    int co  = rem / CinPad;
    int ci  = rem - co * CinPad;
    float v = 0.f;
    if (co < Cout && ci < Cin)
        v = w[((size_t)co * Cin + ci) * KTAP + d];
    Wbf[idx] = f2bf(v);
}

// ---------------- input converter (transpose + pad) ----------------
__global__ __launch_bounds__(256) void convert_inp(
    const float* __restrict__ in, unsigned short* __restrict__ Xt,
    int C, int CinPad, int T, int Trow, int PAD)
{
    __shared__ float s[32][33];
    int b = blockIdx.z, ci0 = blockIdx.y * 32, tr0 = blockIdx.x * 32;
    int tx = threadIdx.x & 31, ty = threadIdx.x >> 5;
#pragma unroll
    for (int i = 0; i < 4; i++) {
        int c = ci0 + ty + 8 * i;
        int t_in = tr0 + tx - PAD;
        float v = (c < C && t_in >= 0 && t_in < T)
                    ? in[((size_t)b * C + c) * T + t_in] : 0.f;
        s[ty + 8 * i][tx] = v;
    }
    __syncthreads();
#pragma unroll
    for (int i = 0; i < 4; i++) {
        int tr = tr0 + ty + 8 * i;
        if (tr < Trow)
            Xt[((size_t)b * Trow + tr) * CinPad + ci0 + tx] = f2bf(s[tx][ty + 8 * i]);
    }
}

__global__ __launch_bounds__(256) void zero_tail_k(unsigned short* __restrict__ Xk)
{
    int i = blockIdx.x * 256 + threadIdx.x;
    if (i < 4 * 512) Xk[(size_t)12928 * 512 + i] = 0;
}
__global__ __launch_bounds__(256) void zero_tail_q(unsigned short* __restrict__ Xq)
{
    int i = blockIdx.x * 256 + threadIdx.x;
    if (i < 4 * 96) Xq[(size_t)51328 * 96 + i] = 0;
}

// ---------------- generic conv-as-GEMM, bf16 MFMA, double-buffered ----------
// A = Wbf [KTAP][CoutAlloc][CinPad], B = Xt rows (n + d), K = KTAP*CinPad.
// out bf16 [(b*Tout+t)*OutStride + co], zero-fill co in [Cout, OutStride).
// 1D grid (nTiles*nCo blocks), XCD-bijective swizzle, co-fastest order.
template <int KTAP, bool RELU>
__global__ __launch_bounds__(256) void conv_mfma(
    const unsigned short* __restrict__ Wbf,
    const unsigned short* __restrict__ Xt,
    const float* __restrict__ bias,
    unsigned short* __restrict__ out,
    int CinPad, int CoutAlloc, int Cout, int Trow, int Tout, int OutStride,
    int nCo)
{
    constexpr int TRW = 136;
    __shared__ unsigned short lds[16384]; // A0[4096] B0[4096] A1[4096] B1[4096]

    const int tid  = threadIdx.x;
    const int lane = tid & 63;
    const int wid  = tid >> 6;
    const int wm   = wid >> 1;
    const int wn   = wid & 1;

    // XCD-bijective swizzle (m204): each XCD owns a contiguous wgid chunk;
    // wgid ordered co-fastest so one X-tile is reused by all co-tiles in-L2.
    const int nwg = gridDim.x;
    const int q8  = nwg >> 3, r8 = nwg & 7;
    const int xcd = blockIdx.x & 7, ix = blockIdx.x >> 3;
    const int wgid = (xcd < r8 ? xcd * (q8 + 1) : r8 * (q8 + 1) + (xcd - r8) * q8) + ix;
    const int co0 = (wgid % nCo) * 128;
    const int n0  = (wgid / nCo) * 128;

    const int srow = lane >> 2;        // staging sub-row 0..15
    const int scol = (lane & 3) * 8;   // ci sub-offset
    const int fr   = lane & 15;
    const int ko   = (lane >> 4) * 8;

    const int nKc   = CinPad >> 5;
    const int nIter = KTAP * nKc;

    f32x4 acc[4][4] = {};

    // staging index state (tile currently being staged)
    int cc = 0, d = 0;
#define STAGE(buf)                                                              \
    {                                                                           \
        int ci0s = cc * 32;                                                     \
        const unsigned short* asrc =                                            \
            Wbf + ((size_t)d * CoutAlloc + co0 + wid * 32 + srow) * CinPad + ci0s + scol; \
        const unsigned short* bsrc =                                            \
            Xt + ((size_t)(n0 + d) + wid * 32 + srow) * CinPad + ci0s + scol;   \
        unsigned short* Ab = lds + (buf) * 8192;                                \
        unsigned short* Bb = Ab + 4096;                                         \
        GLOAD16(asrc,                       &Ab[wid * 1024]);                   \
        GLOAD16(asrc + (size_t)16 * CinPad, &Ab[wid * 1024 + 512]);             \
        GLOAD16(bsrc,                       &Bb[wid * 1024]);                   \
        GLOAD16(bsrc + (size_t)16 * CinPad, &Bb[wid * 1024 + 512]);             \
        cc++; if (cc == nKc) { cc = 0; d++; }                                   \
    }

#define COMPUTE(buf)                                                            \
    {                                                                           \
        const unsigned short* Ab = lds + (buf) * 8192;                          \
        const unsigned short* Bb = Ab + 4096;                                   \
        bf16x8 af[4], bfr[4];                                                   \
        _Pragma("unroll")                                                       \
        for (int mi = 0; mi < 4; mi++)                                          \
            af[mi] = *(const bf16x8*)&Ab[(wm * 64 + mi * 16 + fr) * 32 + ko];   \
        _Pragma("unroll")                                                       \
        for (int ni = 0; ni < 4; ni++)                                          \
            bfr[ni] = *(const bf16x8*)&Bb[(wn * 64 + ni * 16 + fr) * 32 + ko];  \
        _Pragma("unroll")                                                       \
        for (int mi = 0; mi < 4; mi++)                                          \
            _Pragma("unroll")                                                   \
            for (int ni = 0; ni < 4; ni++)                                      \
                acc[mi][ni] = __builtin_amdgcn_mfma_f32_16x16x32_bf16(          \
                    af[mi], bfr[ni], acc[mi][ni], 0, 0, 0);                     \
    }

    // prologue: stage tile 0, wait
    STAGE(0);
    __syncthreads(); // vmcnt(0) drained by compiler before barrier

    int buf = 0;
    for (int kk = 0; kk < nIter - 1; kk++) {
        STAGE(buf ^ 1);     // issue next tile's loads (stay in flight)
        COMPUTE(buf);       // ds_read + MFMA overlap the loads
        __syncthreads();    // drains vmcnt(0): next tile ready; ds_reads done
        buf ^= 1;
    }
    COMPUTE(buf);

#undef STAGE
#undef COMPUTE

    // two-pass LDS-transpose epilogue -> contiguous bf16 row writes
    int cw = OutStride - co0; if (cw > 128) cw = 128;
#pragma unroll
    for (int p = 0; p < 2; p++) {
        __syncthreads();
        if (wn == p) {
#pragma unroll
            for (int mi = 0; mi < 4; mi++) {
                int col = wm * 64 + mi * 16 + (lane >> 4) * 4;
#pragma unroll
                for (int ni = 0; ni < 4; ni++) {
                    int row = ni * 16 + fr;
                    unsigned short pk[4];
#pragma unroll
                    for (int r = 0; r < 4; r++) {
                        int co = co0 + col + r;
                        float v = 0.f;
                        if (co < Cout) {
                            v = acc[mi][ni][r] + bias[co];
                            if (RELU) v = fmaxf(v, 0.f);
                        }
                        pk[r] = f2bf(v);
                    }
                    *(unsigned long long*)&lds[row * TRW + col] = *(unsigned long long*)pk;
                }
            }
        }
        __syncthreads();
        int rr = tid >> 2;
        int c0 = (tid & 3) * 32;
        int n  = n0 + p * 64 + rr;
        int b  = n / Trow;
        int t  = n - b * Trow;
        if (t < Tout) {
            unsigned short* dst = out + ((size_t)b * Tout + t) * OutStride + co0;
#pragma unroll
            for (int c = c0; c < c0 + 32; c += 8)
                if (c < cw)
                    *(bf16x8*)&dst[c] = *(const bf16x8*)&lds[rr * TRW + c];
        }
    }
}

// ---------------- k2 from bf16 Kt ----------------
__global__ __launch_bounds__(256) void k2_kernel(
    const unsigned short* __restrict__ Kt, float* __restrict__ k2s)
{
    int lane = threadIdx.x & 63, w = threadIdx.x >> 6;
    int row = blockIdx.x * 64 + w * 16 + (lane >> 2);
    int c0 = (lane & 3) * 24;
    const unsigned short* p = Kt + (size_t)row * 96 + c0;
    float s = 0.f;
#pragma unroll
    for (int i = 0; i < 3; i++) {
        bf16x8 v = *(const bf16x8*)&p[i * 8];
#pragma unroll
        for (int e = 0; e < 8; e++) {
            float f = bf2f((unsigned short)v[e]);
            s = fmaf(f, f, s);
        }
    }
    s += __shfl_xor(s, 1);
    s += __shfl_xor(s, 2);
    if ((lane & 3) == 0) k2s[row] = s;
}

// ---------------- fused MFMA-QK + softmax/logprob ----------------
#define NS 7
#define SCW 404
__global__ __launch_bounds__(512) void attn_v2(
    const unsigned short* __restrict__ Kt,   // [32*400][96] bf16
    const unsigned short* __restrict__ Qt,   // [32*1600][96] bf16
    const float* __restrict__ k2s,           // [32*400]
    const float* __restrict__ prior, const int* __restrict__ mask,
    float* __restrict__ out_attn, float* __restrict__ out_lp)
{
    const int T1 = 1600, T2 = 400;
    __shared__ float Sc[32 * SCW];

    const int tid  = threadIdx.x;
    const int lane = tid & 63;
    const int wid  = tid >> 6;
    const int b    = blockIdx.y;
    const int t0   = blockIdx.x * 32;
    const int fr   = lane & 15;
    const int ko   = (lane >> 4) * 8;

    bf16x8 qf[2][3];
#pragma unroll
    for (int ts = 0; ts < 2; ts++)
#pragma unroll
        for (int kk = 0; kk < 3; kk++)
            qf[ts][kk] = *(const bf16x8*)&Qt[((size_t)b * T1 + t0 + ts * 16 + fr) * 96 + kk * 32 + ko];

    for (int st = wid; st < 25; st += 8) {
        f32x4 acc0 = {}, acc1 = {};
#pragma unroll
        for (int kk = 0; kk < 3; kk++) {
            bf16x8 kf = *(const bf16x8*)&Kt[((size_t)b * T2 + st * 16 + fr) * 96 + kk * 32 + ko];
            acc0 = __builtin_amdgcn_mfma_f32_16x16x32_bf16(kf, qf[0][kk], acc0, 0, 0, 0);
            acc1 = __builtin_amdgcn_mfma_f32_16x16x32_bf16(kf, qf[1][kk], acc1, 0, 0, 0);
        }
        int sbase = st * 16 + (lane >> 4) * 4;
        float4 kv = *(const float4*)&k2s[b * T2 + sbase];
        float4 w0, w1;
        w0.x = fmaf(1e-3f, acc0[0], -5e-4f * kv.x);
        w0.y = fmaf(1e-3f, acc0[1], -5e-4f * kv.y);
        w0.z = fmaf(1e-3f, acc0[2], -5e-4f * kv.z);
        w0.w = fmaf(1e-3f, acc0[3], -5e-4f * kv.w);
        w1.x = fmaf(1e-3f, acc1[0], -5e-4f * kv.x);
        w1.y = fmaf(1e-3f, acc1[1], -5e-4f * kv.y);
        w1.z = fmaf(1e-3f, acc1[2], -5e-4f * kv.z);
        w1.w = fmaf(1e-3f, acc1[3], -5e-4f * kv.w);
        *(float4*)&Sc[fr * SCW + sbase]        = w0;
        *(float4*)&Sc[(16 + fr) * SCW + sbase] = w1;
    }

    int mk[NS];
#pragma unroll
    for (int j = 0; j < NS; j++) {
        int s = lane + 64 * j;
        mk[j] = (s < T2) ? mask[b * T2 + s] : 1;
    }

    __syncthreads();

    for (int r = 0; r < 4; r++) {
        int tloc = wid * 4 + r;
        int t = t0 + tloc;

        float scr[NS];
        float m = -INFINITY;
#pragma unroll
        for (int j = 0; j < NS; j++) {
            int s = lane + 64 * j;
            if (s < T2) {
                scr[j] = Sc[tloc * SCW + s];
                m = fmaxf(m, scr[j]);
            } else {
                scr[j] = -INFINITY;
            }
        }
#pragma unroll
        for (int o = 32; o >= 1; o >>= 1) m = fmaxf(m, __shfl_xor(m, o));
        float sum = 0.f;
#pragma unroll
        for (int j = 0; j < NS; j++) {
            int s = lane + 64 * j;
            if (s < T2) sum += __expf(scr[j] - m);
        }
#pragma unroll
        for (int o = 32; o >= 1; o >>= 1) sum += __shfl_xor(sum, o);
        float lse = m + __logf(sum);

        const float* pr = prior + ((size_t)b * T1 + t) * T2;
        float* lpout = out_lp + ((size_t)b * T1 + t) * T2;
        float* atout = out_attn + ((size_t)b * T1 + t) * T2;

        float val[NS];
        float m2 = -INFINITY;
#pragma unroll
        for (int j = 0; j < NS; j++) {
            int s = lane + 64 * j;
            if (s < T2) {
                float lp = scr[j] - lse + __logf(pr[s] + 1e-8f);
                lpout[s] = lp;
                val[j] = mk[j] ? -INFINITY : lp;
                m2 = fmaxf(m2, val[j]);
            } else {
                val[j] = -INFINITY;
            }
        }
#pragma unroll
        for (int o = 32; o >= 1; o >>= 1) m2 = fmaxf(m2, __shfl_xor(m2, o));
        float ex[NS];
        float sum2 = 0.f;
#pragma unroll
        for (int j = 0; j < NS; j++) { ex[j] = __expf(val[j] - m2); sum2 += ex[j]; }
#pragma unroll
        for (int o = 32; o >= 1; o >>= 1) sum2 += __shfl_xor(sum2, o);
        float inv = 1.f / sum2;
#pragma unroll
        for (int j = 0; j < NS; j++) {
            int s = lane + 64 * j;
            if (s < T2) atout[s] = ex[j] * inv;
        }
    }
}

// ---------------------------------------------------------------------------
extern "C" void kernel_launch(void* const* d_in, const int* in_sizes, int n_in,
                              void* d_out, int out_size, void* d_ws, size_t ws_size,
                              hipStream_t stream)
{
    (void)in_sizes; (void)n_in; (void)out_size; (void)ws_size;

    const float* queries = (const float*)d_in[0];
    const float* keys    = (const float*)d_in[1];
    const float* prior   = (const float*)d_in[2];
    const int*   mask    = (const int*)d_in[3];
    const float* kw1     = (const float*)d_in[4];
    const float* kb1     = (const float*)d_in[5];
    const float* kw2     = (const float*)d_in[6];
    const float* kb2     = (const float*)d_in[7];
    const float* qw1     = (const float*)d_in[8];
    const float* qb1     = (const float*)d_in[9];
    const float* qw2     = (const float*)d_in[10];
    const float* qb2     = (const float*)d_in[11];
    const float* qw3     = (const float*)d_in[12];
    const float* qb3     = (const float*)d_in[13];

    float* ws = (float*)d_ws;
    unsigned short* K1t = (unsigned short*)(ws);                 // [12800][1024] bf16
    unsigned short* Q1t = (unsigned short*)(ws);                 // [51200][160] bf16 (reuse)
    unsigned short* Xk  = (unsigned short*)(ws + 6553600);       // [12932][512] bf16
    unsigned short* Xq  = (unsigned short*)(ws + 6553600);       // [51332][96] bf16 (reuse)
    unsigned short* Qt  = (unsigned short*)(ws + 6553600);       // [51200][96] bf16 (reuse)
    unsigned short* Kt  = (unsigned short*)(ws + 9864192);       // [12800][96] bf16
    unsigned short* Q2t = (unsigned short*)(ws + 10479360);      // [51200][96] bf16
    unsigned short* Wk1 = (unsigned short*)(ws + 12936960);      // 3*1024*512
    unsigned short* Wk2 = (unsigned short*)(ws + 13723392);      // 128*1024
    unsigned short* Wq1 = (unsigned short*)(ws + 13788928);      // 3*256*96
    unsigned short* Wq2 = (unsigned short*)(ws + 13825792);      // 128*160
    unsigned short* Wq3 = (unsigned short*)(ws + 13836032);      // 128*96
    float*          k2s = ws + 13842176;                         // 12800 f32

    float* out_attn = (float*)d_out;
    float* out_lp   = out_attn + (size_t)32 * 1600 * 400;

    dim3 blk(256);

    // weight conversions
    convert_wgt<<<(3 * 1024 * 512 + 255) / 256, blk, 0, stream>>>(kw1, Wk1, 1024, 512, 3, 1024, 512);
    convert_wgt<<<(1 * 128 * 1024 + 255) / 256, blk, 0, stream>>>(kw2, Wk2, 80, 1024, 1, 128, 1024);
    convert_wgt<<<(3 * 256 * 96   + 255) / 256, blk, 0, stream>>>(qw1, Wq1, 160, 80, 3, 256, 96);
    convert_wgt<<<(1 * 128 * 160  + 255) / 256, blk, 0, stream>>>(qw2, Wq2, 80, 160, 1, 128, 160);
    convert_wgt<<<(1 * 128 * 96   + 255) / 256, blk, 0, stream>>>(qw3, Wq3, 80, 80, 1, 128, 96);

    // key path
    convert_inp<<<dim3(13, 16, 32), blk, 0, stream>>>(keys, Xk, 512, 512, 400, 404, 1);
    zero_tail_k<<<8, blk, 0, stream>>>(Xk);
    conv_mfma<3, true ><<<808, blk, 0, stream>>>(Wk1, Xk, kb1, K1t, 512, 1024, 1024, 404, 400, 1024, 8);
    conv_mfma<1, false><<<100, blk, 0, stream>>>(Wk2, K1t, kb2, Kt, 1024, 128, 80, 400, 400, 96, 1);
    k2_kernel<<<200, blk, 0, stream>>>(Kt, k2s);

    // query path (Xq over dead Xk; Q1t over dead K1t; Qt over dead Xq)
    convert_inp<<<dim3(51, 3, 32), blk, 0, stream>>>(queries, Xq, 80, 96, 1600, 1604, 1);
    zero_tail_q<<<8, blk, 0, stream>>>(Xq);
    conv_mfma<3, true ><<<802, blk, 0, stream>>>(Wq1, Xq, qb1, Q1t, 96, 256, 160, 1604, 1600, 160, 2);
    conv_mfma<1, true ><<<400, blk, 0, stream>>>(Wq2, Q1t, qb2, Q2t, 160, 128, 80, 1600, 1600, 96, 1);
    conv_mfma<1, false><<<400, blk, 0, stream>>>(Wq3, Q2t, qb3, Qt, 96, 128, 80, 1600, 1600, 96, 1);

    // fused attention + softmaxes
    attn_v2<<<dim3(50, 32), dim3(512), 0, stream>>>(Kt, Qt, k2s, prior, mask, out_attn, out_lp);
}

// Round 7
// 307.358 us; speedup vs baseline: 1.1039x; 1.0458x over previous
//
#include <hip/hip_runtime.h>
#include <math.h>

// ---------------------------------------------------------------------------
// ConvAttention (B=32, T1=1600, T2=400, n_mel=80, n_text=512, n_att=80)
// Round 7: conv_mfma = reg-staged prefetch (r4 loop, full-iter load slack)
//   + XCD-bijective co-fastest swizzle (r6, FETCH 164->27MB) + 20.5KB LDS.
//   q-conv2+q-conv3 fused into one kernel (conv_q23).
//   k2 folded into key-conv2 epilogue.
// ---------------------------------------------------------------------------

typedef __attribute__((ext_vector_type(8))) short bf16x8;
typedef __attribute__((ext_vector_type(4))) float f32x4;

static __device__ __forceinline__ unsigned short f2bf(float f) {
    union { float f; unsigned u; } v; v.f = f;
    unsigned r = v.u + 0x7FFF + ((v.u >> 16) & 1);
    return (unsigned short)(r >> 16);
}
static __device__ __forceinline__ float bf2f(unsigned short h) {
    union { unsigned u; float f; } v; v.u = ((unsigned)h) << 16;
    return v.f;
}

// ---------------- weight converter ----------------
__global__ __launch_bounds__(256) void convert_wgt(
    const float* __restrict__ w, unsigned short* __restrict__ Wbf,
    int Cout, int Cin, int KTAP, int CoutAlloc, int CinPad)
{
    int idx = blockIdx.x * 256 + threadIdx.x;
    int total = KTAP * CoutAlloc * CinPad;
    if (idx >= total) return;
    int d   = idx / (CoutAlloc * CinPad);
    int rem = idx - d * (CoutAlloc * CinPad);
    int co  = rem / CinPad;
    int ci  = rem - co * CinPad;
    float v = 0.f;
    if (co < Cout && ci < Cin)
        v = w[((size_t)co * Cin + ci) * KTAP + d];
    Wbf[idx] = f2bf(v);
}

// ---------------- input converter (transpose + pad) ----------------
__global__ __launch_bounds__(256) void convert_inp(
    const float* __restrict__ in, unsigned short* __restrict__ Xt,
    int C, int CinPad, int T, int Trow, int PAD)
{
    __shared__ float s[32][33];
    int b = blockIdx.z, ci0 = blockIdx.y * 32, tr0 = blockIdx.x * 32;
    int tx = threadIdx.x & 31, ty = threadIdx.x >> 5;
#pragma unroll
    for (int i = 0; i < 4; i++) {
        int c = ci0 + ty + 8 * i;
        int t_in = tr0 + tx - PAD;
        float v = (c < C && t_in >= 0 && t_in < T)
                    ? in[((size_t)b * C + c) * T + t_in] : 0.f;
        s[ty + 8 * i][tx] = v;
    }
    __syncthreads();
#pragma unroll
    for (int i = 0; i < 4; i++) {
        int tr = tr0 + ty + 8 * i;
        if (tr < Trow)
            Xt[((size_t)b * Trow + tr) * CinPad + ci0 + tx] = f2bf(s[tx][ty + 8 * i]);
    }
}

__global__ __launch_bounds__(256) void zero_tail_k(unsigned short* __restrict__ Xk)
{
    int i = blockIdx.x * 256 + threadIdx.x;
    if (i < 4 * 512) Xk[(size_t)12928 * 512 + i] = 0;
}
__global__ __launch_bounds__(256) void zero_tail_q(unsigned short* __restrict__ Xq)
{
    int i = blockIdx.x * 256 + threadIdx.x;
    if (i < 4 * 96) Xq[(size_t)51328 * 96 + i] = 0;
}

// ---------------- generic conv-as-GEMM, bf16 MFMA, reg-staged ----------
// A = Wbf [KTAP][CoutAlloc][CinPad], B = Xt rows (n + d), K = KTAP*CinPad.
// out bf16 [(b*Tout+t)*OutStride + co], zero-fill co in [Cout, OutStride).
// Optional k2s: per-row sum of squares over co (needs CoutAlloc==OutStride tile,
// i.e. nCo==1 covering all channels; zero-fill makes pad channels harmless).
template <int KTAP, bool RELU>
__global__ __launch_bounds__(256) void conv_mfma(
    const unsigned short* __restrict__ Wbf,
    const unsigned short* __restrict__ Xt,
    const float* __restrict__ bias,
    unsigned short* __restrict__ out,
    float* __restrict__ k2s,
    int CinPad, int CoutAlloc, int Cout, int Trow, int Tout, int OutStride,
    int nCo)
{
    constexpr int LDW = 40;   // staged LDS row stride (32+8 pad, conflict-free)
    constexpr int TRW = 136;  // transpose-epilogue row stride
    __shared__ unsigned short lds[10240]; // Al[5120] Bl[5120]; epilogue 8704 aliases
    unsigned short* Al = lds;
    unsigned short* Bl = lds + 128 * LDW;

    const int tid  = threadIdx.x;
    const int lane = tid & 63;
    const int wid  = tid >> 6;
    const int wm   = wid >> 1;
    const int wn   = wid & 1;

    // XCD-bijective swizzle (m204), co-fastest order for per-XCD L2 reuse
    const int nwg = gridDim.x;
    const int q8  = nwg >> 3, r8 = nwg & 7;
    const int xcd = blockIdx.x & 7, ix = blockIdx.x >> 3;
    const int wgid = (xcd < r8 ? xcd * (q8 + 1) : r8 * (q8 + 1) + (xcd - r8) * q8) + ix;
    const int co0 = (wgid % nCo) * 128;
    const int n0  = (wgid / nCo) * 128;

    const int r0 = tid >> 2;          // staging rows 0..63
    const int r1 = r0 + 64;           // 64..127
    const int q0 = (tid & 3) * 8;     // ci sub-offset
    const int fr = lane & 15;
    const int ko = (lane >> 4) * 8;

    const int nKc   = CinPad >> 5;
    const int nIter = KTAP * nKc;

    f32x4 acc[4][4] = {};

    // register prefetch of tile 0 (full-iteration slack before consumption)
    bf16x8 ra0 = *(const bf16x8*)&Wbf[(size_t)(co0 + r0) * CinPad + q0];
    bf16x8 ra1 = *(const bf16x8*)&Wbf[(size_t)(co0 + r1) * CinPad + q0];
    bf16x8 rb0 = *(const bf16x8*)&Xt[(size_t)(n0 + r0) * CinPad + q0];
    bf16x8 rb1 = *(const bf16x8*)&Xt[(size_t)(n0 + r1) * CinPad + q0];

    int cc = 0, d = 0;
    for (int kk = 0; kk < nIter; kk++) {
        __syncthreads();
        *(bf16x8*)&Al[r0 * LDW + q0] = ra0;
        *(bf16x8*)&Al[r1 * LDW + q0] = ra1;
        *(bf16x8*)&Bl[r0 * LDW + q0] = rb0;
        *(bf16x8*)&Bl[r1 * LDW + q0] = rb1;
        __syncthreads();

        int ccn = cc + 1, dn = d;
        if (ccn == nKc) { ccn = 0; dn++; }
        if (kk < nIter - 1) {
            int ci0 = ccn * 32;
            ra0 = *(const bf16x8*)&Wbf[((size_t)dn * CoutAlloc + co0 + r0) * CinPad + ci0 + q0];
            ra1 = *(const bf16x8*)&Wbf[((size_t)dn * CoutAlloc + co0 + r1) * CinPad + ci0 + q0];
            rb0 = *(const bf16x8*)&Xt[(size_t)(n0 + dn + r0) * CinPad + ci0 + q0];
            rb1 = *(const bf16x8*)&Xt[(size_t)(n0 + dn + r1) * CinPad + ci0 + q0];
        }

        bf16x8 af[4], bfr[4];
#pragma unroll
        for (int mi = 0; mi < 4; mi++)
            af[mi] = *(const bf16x8*)&Al[(wm * 64 + mi * 16 + fr) * LDW + ko];
#pragma unroll
        for (int ni = 0; ni < 4; ni++)
            bfr[ni] = *(const bf16x8*)&Bl[(wn * 64 + ni * 16 + fr) * LDW + ko];
#pragma unroll
        for (int mi = 0; mi < 4; mi++)
#pragma unroll
            for (int ni = 0; ni < 4; ni++)
                acc[mi][ni] = __builtin_amdgcn_mfma_f32_16x16x32_bf16(
                    af[mi], bfr[ni], acc[mi][ni], 0, 0, 0);

        cc = ccn; d = dn;
    }

    // two-pass LDS-transpose epilogue -> contiguous bf16 row writes (+ opt k2)
    int cw = OutStride - co0; if (cw > 128) cw = 128;
#pragma unroll
    for (int p = 0; p < 2; p++) {
        __syncthreads();
        if (wn == p) {
#pragma unroll
            for (int mi = 0; mi < 4; mi++) {
                int col = wm * 64 + mi * 16 + (lane >> 4) * 4;
#pragma unroll
                for (int ni = 0; ni < 4; ni++) {
                    int row = ni * 16 + fr;
                    unsigned short pk[4];
#pragma unroll
                    for (int r = 0; r < 4; r++) {
                        int co = co0 + col + r;
                        float v = 0.f;
                        if (co < Cout) {
                            v = acc[mi][ni][r] + bias[co];
                            if (RELU) v = fmaxf(v, 0.f);
                        }
                        pk[r] = f2bf(v);
                    }
                    *(unsigned long long*)&lds[row * TRW + col] = *(unsigned long long*)pk;
                }
            }
        }
        __syncthreads();
        int rr = tid >> 2;
        int c0 = (tid & 3) * 32;
        int n  = n0 + p * 64 + rr;
        int b  = n / Trow;
        int t  = n - b * Trow;
        if (t < Tout) {
            unsigned short* dst = out + ((size_t)b * Tout + t) * OutStride + co0;
#pragma unroll
            for (int c = c0; c < c0 + 32; c += 8)
                if (c < cw)
                    *(bf16x8*)&dst[c] = *(const bf16x8*)&lds[rr * TRW + c];
        }
        if (k2s != nullptr) {
            float s = 0.f;
            if (c0 < 96) {
#pragma unroll
                for (int c = c0; c < c0 + 32 && c < 96; c += 8) {
                    bf16x8 v = *(const bf16x8*)&lds[rr * TRW + c];
#pragma unroll
                    for (int e = 0; e < 8; e++) {
                        float f = bf2f((unsigned short)v[e]);
                        s = fmaf(f, f, s);
                    }
                }
            }
            s += __shfl_xor(s, 1);
            s += __shfl_xor(s, 2);
            if ((tid & 3) == 0 && t < Tout) k2s[n] = s;
        }
    }
}

// ---------------- fused q-conv2 + q-conv3 (both 1-tap) ----------------
// stage1: acc = W2[128a][160] x Q1t[n][160]; relu -> X2 LDS [128n][96(+pad)]
// stage2: acc = W3[128a][96]  x X2;          -> Qt [(n)*96 + co]
__global__ __launch_bounds__(256) void conv_q23(
    const unsigned short* __restrict__ W2,   // [128][160]
    const unsigned short* __restrict__ W3,   // [128][96]
    const float* __restrict__ b2, const float* __restrict__ b3,
    const unsigned short* __restrict__ Q1t,  // [51200][160]
    unsigned short* __restrict__ Qt)         // [51200][96]
{
    constexpr int LDW = 40, TRW = 136, X2W = 104;
    __shared__ unsigned short lds[10240 + 128 * X2W]; // Al|Bl|X2
    unsigned short* Al = lds;
    unsigned short* Bl = lds + 5120;
    unsigned short* X2 = lds + 10240;

    const int tid  = threadIdx.x;
    const int lane = tid & 63;
    const int wid  = tid >> 6;
    const int wm   = wid >> 1;
    const int wn   = wid & 1;
    const int n0   = blockIdx.x * 128;

    const int r0 = tid >> 2;
    const int r1 = r0 + 64;
    const int q0 = (tid & 3) * 8;
    const int fr = lane & 15;
    const int ko = (lane >> 4) * 8;

    f32x4 acc[4][4] = {};

    // ---- stage 1: K = 160 (5 chunks) ----
    bf16x8 ra0 = *(const bf16x8*)&W2[(size_t)r0 * 160 + q0];
    bf16x8 ra1 = *(const bf16x8*)&W2[(size_t)r1 * 160 + q0];
    bf16x8 rb0 = *(const bf16x8*)&Q1t[(size_t)(n0 + r0) * 160 + q0];
    bf16x8 rb1 = *(const bf16x8*)&Q1t[(size_t)(n0 + r1) * 160 + q0];

    for (int kk = 0; kk < 5; kk++) {
        __syncthreads();
        *(bf16x8*)&Al[r0 * LDW + q0] = ra0;
        *(bf16x8*)&Al[r1 * LDW + q0] = ra1;
        *(bf16x8*)&Bl[r0 * LDW + q0] = rb0;
        *(bf16x8*)&Bl[r1 * LDW + q0] = rb1;
        __syncthreads();

        if (kk < 4) {
            int ci0 = (kk + 1) * 32;
            ra0 = *(const bf16x8*)&W2[(size_t)r0 * 160 + ci0 + q0];
            ra1 = *(const bf16x8*)&W2[(size_t)r1 * 160 + ci0 + q0];
            rb0 = *(const bf16x8*)&Q1t[(size_t)(n0 + r0) * 160 + ci0 + q0];
            rb1 = *(const bf16x8*)&Q1t[(size_t)(n0 + r1) * 160 + ci0 + q0];
        }

        bf16x8 af[4], bfr[4];
#pragma unroll
        for (int mi = 0; mi < 4; mi++)
            af[mi] = *(const bf16x8*)&Al[(wm * 64 + mi * 16 + fr) * LDW + ko];
#pragma unroll
        for (int ni = 0; ni < 4; ni++)
            bfr[ni] = *(const bf16x8*)&Bl[(wn * 64 + ni * 16 + fr) * LDW + ko];
#pragma unroll
        for (int mi = 0; mi < 4; mi++)
#pragma unroll
            for (int ni = 0; ni < 4; ni++)
                acc[mi][ni] = __builtin_amdgcn_mfma_f32_16x16x32_bf16(
                    af[mi], bfr[ni], acc[mi][ni], 0, 0, 0);
    }

    // ---- mid: X2[n][co] = relu(acc + b2)  (co<80; zero-fill 80..95) ----
#pragma unroll
    for (int mi = 0; mi < 4; mi++) {
        int col = wm * 64 + mi * 16 + (lane >> 4) * 4;
        if (col >= 96) continue;
#pragma unroll
        for (int ni = 0; ni < 4; ni++) {
            int row = wn * 64 + ni * 16 + fr;
            unsigned short pk[4];
#pragma unroll
            for (int r = 0; r < 4; r++) {
                int co = col + r;
                float v = 0.f;
                if (co < 80) v = fmaxf(acc[mi][ni][r] + b2[co], 0.f);
                pk[r] = f2bf(v);
            }
            *(unsigned long long*)&X2[row * X2W + col] = *(unsigned long long*)pk;
        }
    }

    // ---- stage 2: K = 96 (3 chunks), A = W3, B = X2 (in LDS) ----
#pragma unroll
    for (int mi = 0; mi < 4; mi++)
#pragma unroll
        for (int ni = 0; ni < 4; ni++)
            acc[mi][ni] = (f32x4){0.f, 0.f, 0.f, 0.f};

    ra0 = *(const bf16x8*)&W3[(size_t)r0 * 96 + q0];
    ra1 = *(const bf16x8*)&W3[(size_t)r1 * 96 + q0];

    for (int kk = 0; kk < 3; kk++) {
        __syncthreads(); // covers X2 writes (kk=0) and prior Al reads
        *(bf16x8*)&Al[r0 * LDW + q0] = ra0;
        *(bf16x8*)&Al[r1 * LDW + q0] = ra1;
        __syncthreads();

        if (kk < 2) {
            int ci0 = (kk + 1) * 32;
            ra0 = *(const bf16x8*)&W3[(size_t)r0 * 96 + ci0 + q0];
            ra1 = *(const bf16x8*)&W3[(size_t)r1 * 96 + ci0 + q0];
        }

        bf16x8 af[4], bfr[4];
#pragma unroll
        for (int mi = 0; mi < 4; mi++)
            af[mi] = *(const bf16x8*)&Al[(wm * 64 + mi * 16 + fr) * LDW + ko];
#pragma unroll
        for (int ni = 0; ni < 4; ni++)
            bfr[ni] = *(const bf16x8*)&X2[(wn * 64 + ni * 16 + fr) * X2W + kk * 32 + ko];
#pragma unroll
        for (int mi = 0; mi < 4; mi++)
#pragma unroll
            for (int ni = 0; ni < 4; ni++)
                acc[mi][ni] = __builtin_amdgcn_mfma_f32_16x16x32_bf16(
                    af[mi], bfr[ni], acc[mi][ni], 0, 0, 0);
    }

    // ---- epilogue: two-pass transpose -> Qt (Cout=80, stride 96) ----
#pragma unroll
    for (int p = 0; p < 2; p++) {
        __syncthreads();
        if (wn == p) {
#pragma unroll
            for (int mi = 0; mi < 4; mi++) {
                int col = wm * 64 + mi * 16 + (lane >> 4) * 4;
#pragma unroll
                for (int ni = 0; ni < 4; ni++) {
                    int row = ni * 16 + fr;
                    unsigned short pk[4];
#pragma unroll
                    for (int r = 0; r < 4; r++) {
                        int co = col + r;
                        float v = 0.f;
                        if (co < 80) v = acc[mi][ni][r] + b3[co];
                        pk[r] = f2bf(v);
                    }
                    *(unsigned long long*)&lds[row * TRW + col] = *(unsigned long long*)pk;
                }
            }
        }
        __syncthreads();
        int rr = tid >> 2;
        int c0 = (tid & 3) * 32;
        int n  = n0 + p * 64 + rr;
        unsigned short* dst = Qt + (size_t)n * 96;
#pragma unroll
        for (int c = c0; c < c0 + 32; c += 8)
            if (c < 96)
                *(bf16x8*)&dst[c] = *(const bf16x8*)&lds[rr * TRW + c];
    }
}

// ---------------- fused MFMA-QK + softmax/logprob ----------------
#define NS 7
#define SCW 404
__global__ __launch_bounds__(512) void attn_v2(
    const unsigned short* __restrict__ Kt,   // [32*400][96] bf16
    const unsigned short* __restrict__ Qt,   // [32*1600][96] bf16
    const float* __restrict__ k2s,           // [32*400]
    const float* __restrict__ prior, const int* __restrict__ mask,
    float* __restrict__ out_attn, float* __restrict__ out_lp)
{
    const int T1 = 1600, T2 = 400;
    __shared__ float Sc[32 * SCW];

    const int tid  = threadIdx.x;
    const int lane = tid & 63;
    const int wid  = tid >> 6;
    const int b    = blockIdx.y;
    const int t0   = blockIdx.x * 32;
    const int fr   = lane & 15;
    const int ko   = (lane >> 4) * 8;

    bf16x8 qf[2][3];
#pragma unroll
    for (int ts = 0; ts < 2; ts++)
#pragma unroll
        for (int kk = 0; kk < 3; kk++)
            qf[ts][kk] = *(const bf16x8*)&Qt[((size_t)b * T1 + t0 + ts * 16 + fr) * 96 + kk * 32 + ko];

    for (int st = wid; st < 25; st += 8) {
        f32x4 acc0 = {}, acc1 = {};
#pragma unroll
        for (int kk = 0; kk < 3; kk++) {
            bf16x8 kf = *(const bf16x8*)&Kt[((size_t)b * T2 + st * 16 + fr) * 96 + kk * 32 + ko];
            acc0 = __builtin_amdgcn_mfma_f32_16x16x32_bf16(kf, qf[0][kk], acc0, 0, 0, 0);
            acc1 = __builtin_amdgcn_mfma_f32_16x16x32_bf16(kf, qf[1][kk], acc1, 0, 0, 0);
        }
        int sbase = st * 16 + (lane >> 4) * 4;
        float4 kv = *(const float4*)&k2s[b * T2 + sbase];
        float4 w0, w1;
        w0.x = fmaf(1e-3f, acc0[0], -5e-4f * kv.x);
        w0.y = fmaf(1e-3f, acc0[1], -5e-4f * kv.y);
        w0.z = fmaf(1e-3f, acc0[2], -5e-4f * kv.z);
        w0.w = fmaf(1e-3f, acc0[3], -5e-4f * kv.w);
        w1.x = fmaf(1e-3f, acc1[0], -5e-4f * kv.x);
        w1.y = fmaf(1e-3f, acc1[1], -5e-4f * kv.y);
        w1.z = fmaf(1e-3f, acc1[2], -5e-4f * kv.z);
        w1.w = fmaf(1e-3f, acc1[3], -5e-4f * kv.w);
        *(float4*)&Sc[fr * SCW + sbase]        = w0;
        *(float4*)&Sc[(16 + fr) * SCW + sbase] = w1;
    }

    int mk[NS];
#pragma unroll
    for (int j = 0; j < NS; j++) {
        int s = lane + 64 * j;
        mk[j] = (s < T2) ? mask[b * T2 + s] : 1;
    }

    __syncthreads();

    for (int r = 0; r < 4; r++) {
        int tloc = wid * 4 + r;
        int t = t0 + tloc;

        float scr[NS];
        float m = -INFINITY;
#pragma unroll
        for (int j = 0; j < NS; j++) {
            int s = lane + 64 * j;
            if (s < T2) {
                scr[j] = Sc[tloc * SCW + s];
                m = fmaxf(m, scr[j]);
            } else {
                scr[j] = -INFINITY;
            }
        }
#pragma unroll
        for (int o = 32; o >= 1; o >>= 1) m = fmaxf(m, __shfl_xor(m, o));
        float sum = 0.f;
#pragma unroll
        for (int j = 0; j < NS; j++) {
            int s = lane + 64 * j;
            if (s < T2) sum += __expf(scr[j] - m);
        }
#pragma unroll
        for (int o = 32; o >= 1; o >>= 1) sum += __shfl_xor(sum, o);
        float lse = m + __logf(sum);

        const float* pr = prior + ((size_t)b * T1 + t) * T2;
        float* lpout = out_lp + ((size_t)b * T1 + t) * T2;
        float* atout = out_attn + ((size_t)b * T1 + t) * T2;

        float val[NS];
        float m2 = -INFINITY;
#pragma unroll
        for (int j = 0; j < NS; j++) {
            int s = lane + 64 * j;
            if (s < T2) {
                float lp = scr[j] - lse + __logf(pr[s] + 1e-8f);
                lpout[s] = lp;
                val[j] = mk[j] ? -INFINITY : lp;
                m2 = fmaxf(m2, val[j]);
            } else {
                val[j] = -INFINITY;
            }
        }
#pragma unroll
        for (int o = 32; o >= 1; o >>= 1) m2 = fmaxf(m2, __shfl_xor(m2, o));
        float ex[NS];
        float sum2 = 0.f;
#pragma unroll
        for (int j = 0; j < NS; j++) { ex[j] = __expf(val[j] - m2); sum2 += ex[j]; }
#pragma unroll
        for (int o = 32; o >= 1; o >>= 1) sum2 += __shfl_xor(sum2, o);
        float inv = 1.f / sum2;
#pragma unroll
        for (int j = 0; j < NS; j++) {
            int s = lane + 64 * j;
            if (s < T2) atout[s] = ex[j] * inv;
        }
    }
}

// ---------------------------------------------------------------------------
extern "C" void kernel_launch(void* const* d_in, const int* in_sizes, int n_in,
                              void* d_out, int out_size, void* d_ws, size_t ws_size,
                              hipStream_t stream)
{
    (void)in_sizes; (void)n_in; (void)out_size; (void)ws_size;

    const float* queries = (const float*)d_in[0];
    const float* keys    = (const float*)d_in[1];
    const float* prior   = (const float*)d_in[2];
    const int*   mask    = (const int*)d_in[3];
    const float* kw1     = (const float*)d_in[4];
    const float* kb1     = (const float*)d_in[5];
    const float* kw2     = (const float*)d_in[6];
    const float* kb2     = (const float*)d_in[7];
    const float* qw1     = (const float*)d_in[8];
    const float* qb1     = (const float*)d_in[9];
    const float* qw2     = (const float*)d_in[10];
    const float* qb2     = (const float*)d_in[11];
    const float* qw3     = (const float*)d_in[12];
    const float* qb3     = (const float*)d_in[13];

    float* ws = (float*)d_ws;
    unsigned short* K1t = (unsigned short*)(ws);                 // [12800][1024] bf16
    unsigned short* Q1t = (unsigned short*)(ws);                 // [51200][160] bf16 (reuse)
    unsigned short* Xk  = (unsigned short*)(ws + 6553600);       // [12932][512] bf16
    unsigned short* Xq  = (unsigned short*)(ws + 6553600);       // [51332][96] bf16 (reuse)
    unsigned short* Qt  = (unsigned short*)(ws + 6553600);       // [51200][96] bf16 (reuse)
    unsigned short* Kt  = (unsigned short*)(ws + 9864192);       // [12800][96] bf16
    unsigned short* Wk1 = (unsigned short*)(ws + 12936960);      // 3*1024*512
    unsigned short* Wk2 = (unsigned short*)(ws + 13723392);      // 128*1024
    unsigned short* Wq1 = (unsigned short*)(ws + 13788928);      // 3*256*96
    unsigned short* Wq2 = (unsigned short*)(ws + 13825792);      // 128*160
    unsigned short* Wq3 = (unsigned short*)(ws + 13836032);      // 128*96
    float*          k2s = ws + 13842176;                         // 12800 f32

    float* out_attn = (float*)d_out;
    float* out_lp   = out_attn + (size_t)32 * 1600 * 400;

    dim3 blk(256);

    // weight conversions
    convert_wgt<<<(3 * 1024 * 512 + 255) / 256, blk, 0, stream>>>(kw1, Wk1, 1024, 512, 3, 1024, 512);
    convert_wgt<<<(1 * 128 * 1024 + 255) / 256, blk, 0, stream>>>(kw2, Wk2, 80, 1024, 1, 128, 1024);
    convert_wgt<<<(3 * 256 * 96   + 255) / 256, blk, 0, stream>>>(qw1, Wq1, 160, 80, 3, 256, 96);
    convert_wgt<<<(1 * 128 * 160  + 255) / 256, blk, 0, stream>>>(qw2, Wq2, 80, 160, 1, 128, 160);
    convert_wgt<<<(1 * 128 * 96   + 255) / 256, blk, 0, stream>>>(qw3, Wq3, 80, 80, 1, 128, 96);

    // key path
    convert_inp<<<dim3(13, 16, 32), blk, 0, stream>>>(keys, Xk, 512, 512, 400, 404, 1);
    zero_tail_k<<<8, blk, 0, stream>>>(Xk);
    conv_mfma<3, true ><<<808, blk, 0, stream>>>(Wk1, Xk, kb1, K1t, nullptr, 512, 1024, 1024, 404, 400, 1024, 8);
    conv_mfma<1, false><<<100, blk, 0, stream>>>(Wk2, K1t, kb2, Kt, k2s, 1024, 128, 80, 400, 400, 96, 1);

    // query path (Xq over dead Xk; Q1t over dead K1t; Qt over dead Xq)
    convert_inp<<<dim3(51, 3, 32), blk, 0, stream>>>(queries, Xq, 80, 96, 1600, 1604, 1);
    zero_tail_q<<<8, blk, 0, stream>>>(Xq);
    conv_mfma<3, true ><<<802, blk, 0, stream>>>(Wq1, Xq, qb1, Q1t, nullptr, 96, 256, 160, 1604, 1600, 160, 2);
    conv_q23<<<400, blk, 0, stream>>>(Wq2, Wq3, qb2, qb3, Q1t, Qt);

    // fused attention + softmaxes
    attn_v2<<<dim3(50, 32), dim3(512), 0, stream>>>(Kt, Qt, k2s, prior, mask, out_attn, out_lp);
}

// Round 8
// 265.121 us; speedup vs baseline: 1.2798x; 1.1593x over previous
//
#include <hip/hip_runtime.h>
#include <math.h>

// ---------------------------------------------------------------------------
// ConvAttention (B=32, T1=1600, T2=400, n_mel=80, n_text=512, n_att=80)
// Round 8: conv1s -> gemm_conv: 128x256 tile, 8 waves, global_load_lds(16B),
//   depth-2 pipeline with COUNTED vmcnt(3) + raw s_barrier (T3+T4, m218) —
//   loads stay in flight across barriers, no vmcnt(0) drain in main loop.
//   Setup (5 weight converts + 2 tail zeroes) fused into one kernel.
// ---------------------------------------------------------------------------

typedef __attribute__((ext_vector_type(8))) short bf16x8;
typedef __attribute__((ext_vector_type(4))) float f32x4;

static __device__ __forceinline__ unsigned short f2bf(float f) {
    union { float f; unsigned u; } v; v.f = f;
    unsigned r = v.u + 0x7FFF + ((v.u >> 16) & 1);
    return (unsigned short)(r >> 16);
}
static __device__ __forceinline__ float bf2f(unsigned short h) {
    union { unsigned u; float f; } v; v.u = ((unsigned)h) << 16;
    return v.f;
}

#define GLOAD16(g, s) __builtin_amdgcn_global_load_lds( \
    (const __attribute__((address_space(1))) void*)(g), \
    (__attribute__((address_space(3))) void*)(s), 16, 0, 0)

// ---------------- fused setup: all weight converts + input tail zeroes ------
static __device__ __forceinline__ void fill_w(
    const float* __restrict__ w, unsigned short* __restrict__ dst, int rem,
    int Cout, int Cin, int KTAP, int CoutAlloc, int CinPad)
{
    int d  = rem / (CoutAlloc * CinPad);
    int r2 = rem - d * (CoutAlloc * CinPad);
    int co = r2 / CinPad, ci = r2 - co * CinPad;
    float v = (co < Cout && ci < Cin) ? w[((size_t)co * Cin + ci) * KTAP + d] : 0.f;
    dst[rem] = f2bf(v);
}

#define S0 1572864   // Wk1 3*1024*512
#define S1 (S0+131072)   // Wk2 128*1024
#define S2 (S1+73728)    // Wq1 3*256*96
#define S3 (S2+20480)    // Wq2 128*160
#define S4 (S3+12288)    // Wq3 128*96
#define S5 (S4+66560)    // Xk tail 130*512
#define S6 (S5+12480)    // Xq tail 130*96

__global__ __launch_bounds__(256) void setup_kernel(
    const float* __restrict__ kw1, const float* __restrict__ kw2,
    const float* __restrict__ qw1, const float* __restrict__ qw2,
    const float* __restrict__ qw3,
    unsigned short* __restrict__ Wk1, unsigned short* __restrict__ Wk2,
    unsigned short* __restrict__ Wq1, unsigned short* __restrict__ Wq2,
    unsigned short* __restrict__ Wq3,
    unsigned short* __restrict__ Xk, unsigned short* __restrict__ Xq)
{
    int idx = blockIdx.x * 256 + threadIdx.x;
    if (idx < S0)      fill_w(kw1, Wk1, idx,       1024, 512, 3, 1024, 512);
    else if (idx < S1) fill_w(kw2, Wk2, idx - S0,  80, 1024, 1, 128, 1024);
    else if (idx < S2) fill_w(qw1, Wq1, idx - S1,  160, 80, 3, 256, 96);
    else if (idx < S3) fill_w(qw2, Wq2, idx - S2,  80, 160, 1, 128, 160);
    else if (idx < S4) fill_w(qw3, Wq3, idx - S3,  80, 80, 1, 128, 96);
    else if (idx < S5) Xk[(size_t)12928 * 512 + (idx - S4)] = 0;
    else if (idx < S6) Xq[(size_t)51328 * 96  + (idx - S5)] = 0;
}

// ---------------- input converter (transpose + pad) ----------------
__global__ __launch_bounds__(256) void convert_inp(
    const float* __restrict__ in, unsigned short* __restrict__ Xt,
    int C, int CinPad, int T, int Trow, int PAD)
{
    __shared__ float s[32][33];
    int b = blockIdx.z, ci0 = blockIdx.y * 32, tr0 = blockIdx.x * 32;
    int tx = threadIdx.x & 31, ty = threadIdx.x >> 5;
#pragma unroll
    for (int i = 0; i < 4; i++) {
        int c = ci0 + ty + 8 * i;
        int t_in = tr0 + tx - PAD;
        float v = (c < C && t_in >= 0 && t_in < T)
                    ? in[((size_t)b * C + c) * T + t_in] : 0.f;
        s[ty + 8 * i][tx] = v;
    }
    __syncthreads();
#pragma unroll
    for (int i = 0; i < 4; i++) {
        int tr = tr0 + ty + 8 * i;
        if (tr < Trow)
            Xt[((size_t)b * Trow + tr) * CinPad + ci0 + tx] = f2bf(s[tx][ty + 8 * i]);
    }
}

// ---------------- 128x256 conv-GEMM, counted-vmcnt pipeline ----------------
// A = Wbf [KTAP][CoutAlloc][CinPad], B = Xt rows (n + d), K = KTAP*CinPad.
// out bf16 [(b*Tout+t)*OutStride + co]; n valid iff n < Nvalid and t < Tout.
template <int KTAP, bool RELU>
__global__ __launch_bounds__(512) void gemm_conv(
    const unsigned short* __restrict__ Wbf,
    const unsigned short* __restrict__ Xt,
    const float* __restrict__ bias,
    unsigned short* __restrict__ out,
    int CinPad, int CoutAlloc, int Cout, int Trow, int Tout, int OutStride,
    int nCo, int Nvalid)
{
    constexpr int TRW = 136;
    __shared__ unsigned short lds[24576]; // 2 bufs x (A 4096 + B 8192) u16

    const int tid  = threadIdx.x;
    const int lane = tid & 63;
    const int wid  = tid >> 6;
    const int wm   = wid >> 2;   // 0..1  (co 64-half)
    const int wn   = wid & 3;    // 0..3  (n 64-quarter)

    // XCD-bijective swizzle (m204), co-fastest order
    const int nwg = gridDim.x;
    const int q8  = nwg >> 3, r8 = nwg & 7;
    const int xcd = blockIdx.x & 7, ix = blockIdx.x >> 3;
    const int wgid = (xcd < r8 ? xcd * (q8 + 1) : r8 * (q8 + 1) + (xcd - r8) * q8) + ix;
    const int co0 = (wgid % nCo) * 128;
    const int n0  = (wgid / nCo) * 256;

    const int lr = lane >> 2;        // staging sub-row 0..15
    const int lc = (lane & 3) * 8;   // ci sub-offset
    const int fr = lane & 15;
    const int ko = (lane >> 4) * 8;

    const int nKc   = CinPad >> 5;
    const int nIter = KTAP * nKc;

    f32x4 acc[2][4] = {}; // [mi][ni]; wave tile 32co? no: [mi<2? ]
    // wave tile = 64co x 64n -> 4x4 fragments
    f32x4 a4[4][4] = {};

    int scc = 0, sd = 0; // staging (ci-chunk, tap) state
#define STAGE(B)                                                                  \
    {                                                                             \
        const unsigned short* asrc =                                              \
            Wbf + ((size_t)sd * CoutAlloc + co0 + wid * 16 + lr) * CinPad + scc * 32 + lc; \
        const unsigned short* bsrc =                                              \
            Xt + ((size_t)(n0 + sd) + wid * 32 + lr) * CinPad + scc * 32 + lc;    \
        unsigned short* Ab = lds + (B) * 12288;                                   \
        GLOAD16(asrc, &Ab[wid * 512]);                                            \
        GLOAD16(bsrc, &Ab[4096 + wid * 1024]);                                    \
        GLOAD16(bsrc + (size_t)16 * CinPad, &Ab[4096 + wid * 1024 + 512]);        \
        scc++; if (scc == nKc) { scc = 0; sd++; }                                 \
    }

#define COMPUTE(B)                                                                \
    {                                                                             \
        const unsigned short* Ab = lds + (B) * 12288;                             \
        const unsigned short* Bb = Ab + 4096;                                     \
        bf16x8 af[4], bfr[4];                                                     \
        _Pragma("unroll")                                                         \
        for (int mi = 0; mi < 4; mi++)                                            \
            af[mi] = *(const bf16x8*)&Ab[(wm * 64 + mi * 16 + fr) * 32 + ko];     \
        _Pragma("unroll")                                                         \
        for (int ni = 0; ni < 4; ni++)                                            \
            bfr[ni] = *(const bf16x8*)&Bb[(wn * 64 + ni * 16 + fr) * 32 + ko];    \
        _Pragma("unroll")                                                         \
        for (int mi = 0; mi < 4; mi++)                                            \
            _Pragma("unroll")                                                     \
            for (int ni = 0; ni < 4; ni++)                                        \
                a4[mi][ni] = __builtin_amdgcn_mfma_f32_16x16x32_bf16(             \
                    af[mi], bfr[ni], a4[mi][ni], 0, 0, 0);                        \
    }

    // prologue: two tiles in flight
    STAGE(0);
    STAGE(1);

    for (int t = 0; t < nIter; t++) {
        if (t < nIter - 1)
            asm volatile("s_waitcnt vmcnt(3)" ::: "memory"); // tile t done; t+1 in flight
        else
            asm volatile("s_waitcnt vmcnt(0)" ::: "memory");
        __builtin_amdgcn_s_barrier();
        COMPUTE(t & 1);
        __builtin_amdgcn_sched_barrier(0); // pin ds_reads before the barrier
        __builtin_amdgcn_s_barrier();
        if (t + 2 < nIter) STAGE(t & 1);
    }
#undef STAGE
#undef COMPUTE

    __syncthreads(); // full drain before reusing LDS for epilogue

    // four-pass LDS-transpose epilogue (64-n strips) -> contiguous bf16 rows
    int cw = OutStride - co0; if (cw > 128) cw = 128;
#pragma unroll
    for (int p = 0; p < 4; p++) {
        if (wn == p) {
#pragma unroll
            for (int mi = 0; mi < 4; mi++) {
                int col = wm * 64 + mi * 16 + (lane >> 4) * 4;
#pragma unroll
                for (int ni = 0; ni < 4; ni++) {
                    int row = ni * 16 + fr; // 0..63 within strip
                    unsigned short pk[4];
#pragma unroll
                    for (int r = 0; r < 4; r++) {
                        int co = co0 + col + r;
                        float v = 0.f;
                        if (co < Cout) {
                            v = a4[mi][ni][r] + bias[co];
                            if (RELU) v = fmaxf(v, 0.f);
                        }
                        pk[r] = f2bf(v);
                    }
                    *(unsigned long long*)&lds[row * TRW + col] = *(unsigned long long*)pk;
                }
            }
        }
        __syncthreads();
        int row = tid >> 3;
        int c0  = (tid & 7) * 16;
        int n   = n0 + p * 64 + row;
        if (n < Nvalid && c0 < cw) {
            int b = n / Trow;
            int t = n - b * Trow;
            if (t < Tout) {
                unsigned short* dst = out + ((size_t)b * Tout + t) * OutStride + co0 + c0;
                *(bf16x8*)&dst[0] = *(const bf16x8*)&lds[row * TRW + c0];
                *(bf16x8*)&dst[8] = *(const bf16x8*)&lds[row * TRW + c0 + 8];
            }
        }
        __syncthreads();
    }
}

// ---------------- key conv2 (128x128 reg-staged, + k2) ----------------
template <int KTAP, bool RELU>
__global__ __launch_bounds__(256) void conv_mfma(
    const unsigned short* __restrict__ Wbf,
    const unsigned short* __restrict__ Xt,
    const float* __restrict__ bias,
    unsigned short* __restrict__ out,
    float* __restrict__ k2s,
    int CinPad, int CoutAlloc, int Cout, int Trow, int Tout, int OutStride,
    int nCo)
{
    constexpr int LDW = 40;
    constexpr int TRW = 136;
    __shared__ unsigned short lds[10240];
    unsigned short* Al = lds;
    unsigned short* Bl = lds + 128 * LDW;

    const int tid  = threadIdx.x;
    const int lane = tid & 63;
    const int wid  = tid >> 6;
    const int wm   = wid >> 1;
    const int wn   = wid & 1;

    const int nwg = gridDim.x;
    const int q8  = nwg >> 3, r8 = nwg & 7;
    const int xcd = blockIdx.x & 7, ix = blockIdx.x >> 3;
    const int wgid = (xcd < r8 ? xcd * (q8 + 1) : r8 * (q8 + 1) + (xcd - r8) * q8) + ix;
    const int co0 = (wgid % nCo) * 128;
    const int n0  = (wgid / nCo) * 128;

    const int r0 = tid >> 2;
    const int r1 = r0 + 64;
    const int q0 = (tid & 3) * 8;
    const int fr = lane & 15;
    const int ko = (lane >> 4) * 8;

    const int nKc   = CinPad >> 5;
    const int nIter = KTAP * nKc;

    f32x4 acc[4][4] = {};

    bf16x8 ra0 = *(const bf16x8*)&Wbf[(size_t)(co0 + r0) * CinPad + q0];
    bf16x8 ra1 = *(const bf16x8*)&Wbf[(size_t)(co0 + r1) * CinPad + q0];
    bf16x8 rb0 = *(const bf16x8*)&Xt[(size_t)(n0 + r0) * CinPad + q0];
    bf16x8 rb1 = *(const bf16x8*)&Xt[(size_t)(n0 + r1) * CinPad + q0];

    int cc = 0, d = 0;
    for (int kk = 0; kk < nIter; kk++) {
        __syncthreads();
        *(bf16x8*)&Al[r0 * LDW + q0] = ra0;
        *(bf16x8*)&Al[r1 * LDW + q0] = ra1;
        *(bf16x8*)&Bl[r0 * LDW + q0] = rb0;
        *(bf16x8*)&Bl[r1 * LDW + q0] = rb1;
        __syncthreads();

        int ccn = cc + 1, dn = d;
        if (ccn == nKc) { ccn = 0; dn++; }
        if (kk < nIter - 1) {
            int ci0 = ccn * 32;
            ra0 = *(const bf16x8*)&Wbf[((size_t)dn * CoutAlloc + co0 + r0) * CinPad + ci0 + q0];
            ra1 = *(const bf16x8*)&Wbf[((size_t)dn * CoutAlloc + co0 + r1) * CinPad + ci0 + q0];
            rb0 = *(const bf16x8*)&Xt[(size_t)(n0 + dn + r0) * CinPad + ci0 + q0];
            rb1 = *(const bf16x8*)&Xt[(size_t)(n0 + dn + r1) * CinPad + ci0 + q0];
        }

        bf16x8 af[4], bfr[4];
#pragma unroll
        for (int mi = 0; mi < 4; mi++)
            af[mi] = *(const bf16x8*)&Al[(wm * 64 + mi * 16 + fr) * LDW + ko];
#pragma unroll
        for (int ni = 0; ni < 4; ni++)
            bfr[ni] = *(const bf16x8*)&Bl[(wn * 64 + ni * 16 + fr) * LDW + ko];
#pragma unroll
        for (int mi = 0; mi < 4; mi++)
#pragma unroll
            for (int ni = 0; ni < 4; ni++)
                acc[mi][ni] = __builtin_amdgcn_mfma_f32_16x16x32_bf16(
                    af[mi], bfr[ni], acc[mi][ni], 0, 0, 0);

        cc = ccn; d = dn;
    }

    int cw = OutStride - co0; if (cw > 128) cw = 128;
#pragma unroll
    for (int p = 0; p < 2; p++) {
        __syncthreads();
        if (wn == p) {
#pragma unroll
            for (int mi = 0; mi < 4; mi++) {
                int col = wm * 64 + mi * 16 + (lane >> 4) * 4;
#pragma unroll
                for (int ni = 0; ni < 4; ni++) {
                    int row = ni * 16 + fr;
                    unsigned short pk[4];
#pragma unroll
                    for (int r = 0; r < 4; r++) {
                        int co = co0 + col + r;
                        float v = 0.f;
                        if (co < Cout) {
                            v = acc[mi][ni][r] + bias[co];
                            if (RELU) v = fmaxf(v, 0.f);
                        }
                        pk[r] = f2bf(v);
                    }
                    *(unsigned long long*)&lds[row * TRW + col] = *(unsigned long long*)pk;
                }
            }
        }
        __syncthreads();
        int rr = tid >> 2;
        int c0 = (tid & 3) * 32;
        int n  = n0 + p * 64 + rr;
        int b  = n / Trow;
        int t  = n - b * Trow;
        if (t < Tout) {
            unsigned short* dst = out + ((size_t)b * Tout + t) * OutStride + co0;
#pragma unroll
            for (int c = c0; c < c0 + 32; c += 8)
                if (c < cw)
                    *(bf16x8*)&dst[c] = *(const bf16x8*)&lds[rr * TRW + c];
        }
        if (k2s != nullptr) {
            float s = 0.f;
            if (c0 < 96) {
#pragma unroll
                for (int c = c0; c < c0 + 32 && c < 96; c += 8) {
                    bf16x8 v = *(const bf16x8*)&lds[rr * TRW + c];
#pragma unroll
                    for (int e = 0; e < 8; e++) {
                        float f = bf2f((unsigned short)v[e]);
                        s = fmaf(f, f, s);
                    }
                }
            }
            s += __shfl_xor(s, 1);
            s += __shfl_xor(s, 2);
            if ((tid & 3) == 0 && t < Tout) k2s[n] = s;
        }
    }
}

// ---------------- fused q-conv2 + q-conv3 (both 1-tap) ----------------
__global__ __launch_bounds__(256) void conv_q23(
    const unsigned short* __restrict__ W2,   // [128][160]
    const unsigned short* __restrict__ W3,   // [128][96]
    const float* __restrict__ b2, const float* __restrict__ b3,
    const unsigned short* __restrict__ Q1t,  // [51200][160]
    unsigned short* __restrict__ Qt)         // [51200][96]
{
    constexpr int LDW = 40, TRW = 136, X2W = 104;
    __shared__ unsigned short lds[10240 + 128 * X2W];
    unsigned short* Al = lds;
    unsigned short* Bl = lds + 5120;
    unsigned short* X2 = lds + 10240;

    const int tid  = threadIdx.x;
    const int lane = tid & 63;
    const int wid  = tid >> 6;
    const int wm   = wid >> 1;
    const int wn   = wid & 1;
    const int n0   = blockIdx.x * 128;

    const int r0 = tid >> 2;
    const int r1 = r0 + 64;
    const int q0 = (tid & 3) * 8;
    const int fr = lane & 15;
    const int ko = (lane >> 4) * 8;

    f32x4 acc[4][4] = {};

    bf16x8 ra0 = *(const bf16x8*)&W2[(size_t)r0 * 160 + q0];
    bf16x8 ra1 = *(const bf16x8*)&W2[(size_t)r1 * 160 + q0];
    bf16x8 rb0 = *(const bf16x8*)&Q1t[(size_t)(n0 + r0) * 160 + q0];
    bf16x8 rb1 = *(const bf16x8*)&Q1t[(size_t)(n0 + r1) * 160 + q0];

    for (int kk = 0; kk < 5; kk++) {
        __syncthreads();
        *(bf16x8*)&Al[r0 * LDW + q0] = ra0;
        *(bf16x8*)&Al[r1 * LDW + q0] = ra1;
        *(bf16x8*)&Bl[r0 * LDW + q0] = rb0;
        *(bf16x8*)&Bl[r1 * LDW + q0] = rb1;
        __syncthreads();

        if (kk < 4) {
            int ci0 = (kk + 1) * 32;
            ra0 = *(const bf16x8*)&W2[(size_t)r0 * 160 + ci0 + q0];
            ra1 = *(const bf16x8*)&W2[(size_t)r1 * 160 + ci0 + q0];
            rb0 = *(const bf16x8*)&Q1t[(size_t)(n0 + r0) * 160 + ci0 + q0];
            rb1 = *(const bf16x8*)&Q1t[(size_t)(n0 + r1) * 160 + ci0 + q0];
        }

        bf16x8 af[4], bfr[4];
#pragma unroll
        for (int mi = 0; mi < 4; mi++)
            af[mi] = *(const bf16x8*)&Al[(wm * 64 + mi * 16 + fr) * LDW + ko];
#pragma unroll
        for (int ni = 0; ni < 4; ni++)
            bfr[ni] = *(const bf16x8*)&Bl[(wn * 64 + ni * 16 + fr) * LDW + ko];
#pragma unroll
        for (int mi = 0; mi < 4; mi++)
#pragma unroll
            for (int ni = 0; ni < 4; ni++)
                acc[mi][ni] = __builtin_amdgcn_mfma_f32_16x16x32_bf16(
                    af[mi], bfr[ni], acc[mi][ni], 0, 0, 0);
    }

#pragma unroll
    for (int mi = 0; mi < 4; mi++) {
        int col = wm * 64 + mi * 16 + (lane >> 4) * 4;
        if (col >= 96) continue;
#pragma unroll
        for (int ni = 0; ni < 4; ni++) {
            int row = wn * 64 + ni * 16 + fr;
            unsigned short pk[4];
#pragma unroll
            for (int r = 0; r < 4; r++) {
                int co = col + r;
                float v = 0.f;
                if (co < 80) v = fmaxf(acc[mi][ni][r] + b2[co], 0.f);
                pk[r] = f2bf(v);
            }
            *(unsigned long long*)&X2[row * X2W + col] = *(unsigned long long*)pk;
        }
    }

#pragma unroll
    for (int mi = 0; mi < 4; mi++)
#pragma unroll
        for (int ni = 0; ni < 4; ni++)
            acc[mi][ni] = (f32x4){0.f, 0.f, 0.f, 0.f};

    ra0 = *(const bf16x8*)&W3[(size_t)r0 * 96 + q0];
    ra1 = *(const bf16x8*)&W3[(size_t)r1 * 96 + q0];

    for (int kk = 0; kk < 3; kk++) {
        __syncthreads();
        *(bf16x8*)&Al[r0 * LDW + q0] = ra0;
        *(bf16x8*)&Al[r1 * LDW + q0] = ra1;
        __syncthreads();

        if (kk < 2) {
            int ci0 = (kk + 1) * 32;
            ra0 = *(const bf16x8*)&W3[(size_t)r0 * 96 + ci0 + q0];
            ra1 = *(const bf16x8*)&W3[(size_t)r1 * 96 + ci0 + q0];
        }

        bf16x8 af[4], bfr[4];
#pragma unroll
        for (int mi = 0; mi < 4; mi++)
            af[mi] = *(const bf16x8*)&Al[(wm * 64 + mi * 16 + fr) * LDW + ko];
#pragma unroll
        for (int ni = 0; ni < 4; ni++)
            bfr[ni] = *(const bf16x8*)&X2[(wn * 64 + ni * 16 + fr) * X2W + kk * 32 + ko];
#pragma unroll
        for (int mi = 0; mi < 4; mi++)
#pragma unroll
            for (int ni = 0; ni < 4; ni++)
                acc[mi][ni] = __builtin_amdgcn_mfma_f32_16x16x32_bf16(
                    af[mi], bfr[ni], acc[mi][ni], 0, 0, 0);
    }

#pragma unroll
    for (int p = 0; p < 2; p++) {
        __syncthreads();
        if (wn == p) {
#pragma unroll
            for (int mi = 0; mi < 4; mi++) {
                int col = wm * 64 + mi * 16 + (lane >> 4) * 4;
#pragma unroll
                for (int ni = 0; ni < 4; ni++) {
                    int row = ni * 16 + fr;
                    unsigned short pk[4];
#pragma unroll
                    for (int r = 0; r < 4; r++) {
                        int co = col + r;
                        float v = 0.f;
                        if (co < 80) v = acc[mi][ni][r] + b3[co];
                        pk[r] = f2bf(v);
                    }
                    *(unsigned long long*)&lds[row * TRW + col] = *(unsigned long long*)pk;
                }
            }
        }
        __syncthreads();
        int rr = tid >> 2;
        int c0 = (tid & 3) * 32;
        int n  = n0 + p * 64 + rr;
        unsigned short* dst = Qt + (size_t)n * 96;
#pragma unroll
        for (int c = c0; c < c0 + 32; c += 8)
            if (c < 96)
                *(bf16x8*)&dst[c] = *(const bf16x8*)&lds[rr * TRW + c];
    }
}

// ---------------- fused MFMA-QK + softmax/logprob ----------------
#define NS 7
#define SCW 404
__global__ __launch_bounds__(512) void attn_v2(
    const unsigned short* __restrict__ Kt,   // [32*400][96] bf16
    const unsigned short* __restrict__ Qt,   // [32*1600][96] bf16
    const float* __restrict__ k2s,           // [32*400]
    const float* __restrict__ prior, const int* __restrict__ mask,
    float* __restrict__ out_attn, float* __restrict__ out_lp)
{
    const int T1 = 1600, T2 = 400;
    __shared__ float Sc[32 * SCW];

    const int tid  = threadIdx.x;
    const int lane = tid & 63;
    const int wid  = tid >> 6;
    const int b    = blockIdx.y;
    const int t0   = blockIdx.x * 32;
    const int fr   = lane & 15;
    const int ko   = (lane >> 4) * 8;

    bf16x8 qf[2][3];
#pragma unroll
    for (int ts = 0; ts < 2; ts++)
#pragma unroll
        for (int kk = 0; kk < 3; kk++)
            qf[ts][kk] = *(const bf16x8*)&Qt[((size_t)b * T1 + t0 + ts * 16 + fr) * 96 + kk * 32 + ko];

    for (int st = wid; st < 25; st += 8) {
        f32x4 acc0 = {}, acc1 = {};
#pragma unroll
        for (int kk = 0; kk < 3; kk++) {
            bf16x8 kf = *(const bf16x8*)&Kt[((size_t)b * T2 + st * 16 + fr) * 96 + kk * 32 + ko];
            acc0 = __builtin_amdgcn_mfma_f32_16x16x32_bf16(kf, qf[0][kk], acc0, 0, 0, 0);
            acc1 = __builtin_amdgcn_mfma_f32_16x16x32_bf16(kf, qf[1][kk], acc1, 0, 0, 0);
        }
        int sbase = st * 16 + (lane >> 4) * 4;
        float4 kv = *(const float4*)&k2s[b * T2 + sbase];
        float4 w0, w1;
        w0.x = fmaf(1e-3f, acc0[0], -5e-4f * kv.x);
        w0.y = fmaf(1e-3f, acc0[1], -5e-4f * kv.y);
        w0.z = fmaf(1e-3f, acc0[2], -5e-4f * kv.z);
        w0.w = fmaf(1e-3f, acc0[3], -5e-4f * kv.w);
        w1.x = fmaf(1e-3f, acc1[0], -5e-4f * kv.x);
        w1.y = fmaf(1e-3f, acc1[1], -5e-4f * kv.y);
        w1.z = fmaf(1e-3f, acc1[2], -5e-4f * kv.z);
        w1.w = fmaf(1e-3f, acc1[3], -5e-4f * kv.w);
        *(float4*)&Sc[fr * SCW + sbase]        = w0;
        *(float4*)&Sc[(16 + fr) * SCW + sbase] = w1;
    }

    int mk[NS];
#pragma unroll
    for (int j = 0; j < NS; j++) {
        int s = lane + 64 * j;
        mk[j] = (s < T2) ? mask[b * T2 + s] : 1;
    }

    __syncthreads();

    for (int r = 0; r < 4; r++) {
        int tloc = wid * 4 + r;
        int t = t0 + tloc;

        float scr[NS];
        float m = -INFINITY;
#pragma unroll
        for (int j = 0; j < NS; j++) {
            int s = lane + 64 * j;
            if (s < T2) {
                scr[j] = Sc[tloc * SCW + s];
                m = fmaxf(m, scr[j]);
            } else {
                scr[j] = -INFINITY;
            }
        }
#pragma unroll
        for (int o = 32; o >= 1; o >>= 1) m = fmaxf(m, __shfl_xor(m, o));
        float sum = 0.f;
#pragma unroll
        for (int j = 0; j < NS; j++) {
            int s = lane + 64 * j;
            if (s < T2) sum += __expf(scr[j] - m);
        }
#pragma unroll
        for (int o = 32; o >= 1; o >>= 1) sum += __shfl_xor(sum, o);
        float lse = m + __logf(sum);

        const float* pr = prior + ((size_t)b * T1 + t) * T2;
        float* lpout = out_lp + ((size_t)b * T1 + t) * T2;
        float* atout = out_attn + ((size_t)b * T1 + t) * T2;

        float val[NS];
        float m2 = -INFINITY;
#pragma unroll
        for (int j = 0; j < NS; j++) {
            int s = lane + 64 * j;
            if (s < T2) {
                float lp = scr[j] - lse + __logf(pr[s] + 1e-8f);
                lpout[s] = lp;
                val[j] = mk[j] ? -INFINITY : lp;
                m2 = fmaxf(m2, val[j]);
            } else {
                val[j] = -INFINITY;
            }
        }
#pragma unroll
        for (int o = 32; o >= 1; o >>= 1) m2 = fmaxf(m2, __shfl_xor(m2, o));
        float ex[NS];
        float sum2 = 0.f;
#pragma unroll
        for (int j = 0; j < NS; j++) { ex[j] = __expf(val[j] - m2); sum2 += ex[j]; }
#pragma unroll
        for (int o = 32; o >= 1; o >>= 1) sum2 += __shfl_xor(sum2, o);
        float inv = 1.f / sum2;
#pragma unroll
        for (int j = 0; j < NS; j++) {
            int s = lane + 64 * j;
            if (s < T2) atout[s] = ex[j] * inv;
        }
    }
}

// ---------------------------------------------------------------------------
extern "C" void kernel_launch(void* const* d_in, const int* in_sizes, int n_in,
                              void* d_out, int out_size, void* d_ws, size_t ws_size,
                              hipStream_t stream)
{
    (void)in_sizes; (void)n_in; (void)out_size; (void)ws_size;

    const float* queries = (const float*)d_in[0];
    const float* keys    = (const float*)d_in[1];
    const float* prior   = (const float*)d_in[2];
    const int*   mask    = (const int*)d_in[3];
    const float* kw1     = (const float*)d_in[4];
    const float* kb1     = (const float*)d_in[5];
    const float* kw2     = (const float*)d_in[6];
    const float* kb2     = (const float*)d_in[7];
    const float* qw1     = (const float*)d_in[8];
    const float* qb1     = (const float*)d_in[9];
    const float* qw2     = (const float*)d_in[10];
    const float* qb2     = (const float*)d_in[11];
    const float* qw3     = (const float*)d_in[12];
    const float* qb3     = (const float*)d_in[13];

    unsigned short* U = (unsigned short*)d_ws;
    unsigned short* K1t = U;                        // [12800][1024]
    unsigned short* Q1t = U;                        // [51200][160] (reuse)
    unsigned short* Xk  = U + 13107200;             // [13058][512]
    unsigned short* Qt  = U + 13107200;             // [51200][96] (reuse after key path)
    unsigned short* Xq  = U + 19792896;             // [51458][96]
    unsigned short* Kt  = U + 24732864;             // [12800][96]
    unsigned short* Wk1 = U + 25961664;             // 3*1024*512
    unsigned short* Wk2 = U + 27534528;             // 128*1024
    unsigned short* Wq1 = U + 27665600;             // 3*256*96
    unsigned short* Wq2 = U + 27739328;             // 128*160
    unsigned short* Wq3 = U + 27759808;             // 128*96
    float*          k2s = (float*)(U + 27772096);   // 12800 f32

    float* out_attn = (float*)d_out;
    float* out_lp   = out_attn + (size_t)32 * 1600 * 400;

    dim3 blk(256);

    // fused setup: all weight converts + Xk/Xq tail zeroes
    setup_kernel<<<(S6 + 255) / 256, blk, 0, stream>>>(
        kw1, kw2, qw1, qw2, qw3, Wk1, Wk2, Wq1, Wq2, Wq3, Xk, Xq);

    // key path
    convert_inp<<<dim3(13, 16, 32), blk, 0, stream>>>(keys, Xk, 512, 512, 400, 404, 1);
    gemm_conv<3, true ><<<408, dim3(512), 0, stream>>>(
        Wk1, Xk, kb1, K1t, 512, 1024, 1024, 404, 400, 1024, 8, 12928);
    conv_mfma<1, false><<<100, blk, 0, stream>>>(
        Wk2, K1t, kb2, Kt, k2s, 1024, 128, 80, 400, 400, 96, 1);

    // query path
    convert_inp<<<dim3(51, 3, 32), blk, 0, stream>>>(queries, Xq, 80, 96, 1600, 1604, 1);
    gemm_conv<3, true ><<<402, dim3(512), 0, stream>>>(
        Wq1, Xq, qb1, Q1t, 96, 256, 160, 1604, 1600, 160, 2, 51328);
    conv_q23<<<400, blk, 0, stream>>>(Wq2, Wq3, qb2, qb3, Q1t, Qt);

    // fused attention + softmaxes
    attn_v2<<<dim3(50, 32), dim3(512), 0, stream>>>(Kt, Qt, k2s, prior, mask, out_attn, out_lp);
}

// Round 9
// 263.889 us; speedup vs baseline: 1.2857x; 1.0047x over previous
//
#include <hip/hip_runtime.h>
#include <math.h>

// ---------------------------------------------------------------------------
// ConvAttention (B=32, T1=1600, T2=400, n_mel=80, n_text=512, n_att=80)
// Round 9: DAG collapsed 8 -> 4 launches (bodies identical to round 8):
//   1) prep_all  = convert_inp(keys) + convert_inp(queries) + weight converts
//   2) conv1_both = gemm_conv(key 408 tiles) + gemm_conv(q 402 tiles), swizzled
//   3) conv2_both = key conv2+k2 (100 blk) || q conv2+conv3 fused (400 blk)
//   4) attn_v2
// ---------------------------------------------------------------------------

typedef __attribute__((ext_vector_type(8))) short bf16x8;
typedef __attribute__((ext_vector_type(4))) float f32x4;

static __device__ __forceinline__ unsigned short f2bf(float f) {
    union { float f; unsigned u; } v; v.f = f;
    unsigned r = v.u + 0x7FFF + ((v.u >> 16) & 1);
    return (unsigned short)(r >> 16);
}
static __device__ __forceinline__ float bf2f(unsigned short h) {
    union { unsigned u; float f; } v; v.u = ((unsigned)h) << 16;
    return v.f;
}

#define GLOAD16(g, s) __builtin_amdgcn_global_load_lds( \
    (const __attribute__((address_space(1))) void*)(g), \
    (__attribute__((address_space(3))) void*)(s), 16, 0, 0)

// ---------------- kernel 1: all prep ----------------
static __device__ __forceinline__ void fill_w(
    const float* __restrict__ w, unsigned short* __restrict__ dst, int rem,
    int Cout, int Cin, int KTAP, int CoutAlloc, int CinPad)
{
    int d  = rem / (CoutAlloc * CinPad);
    int r2 = rem - d * (CoutAlloc * CinPad);
    int co = r2 / CinPad, ci = r2 - co * CinPad;
    float v = (co < Cout && ci < Cin) ? w[((size_t)co * Cin + ci) * KTAP + d] : 0.f;
    dst[rem] = f2bf(v);
}

#define S0 1572864       // Wk1 3*1024*512
#define S1 (S0+131072)   // Wk2 128*1024
#define S2 (S1+73728)    // Wq1 3*256*96
#define S3 (S2+20480)    // Wq2 128*160
#define S4 (S3+12288)    // Wq3 128*96
#define S5 (S4+66560)    // Xk tail 130*512
#define S6 (S5+12480)    // Xq tail 130*96
#define NKB 6656         // 13*16*32 key transpose blocks
#define NQB 4896         // 51*3*32  query transpose blocks
#define NFB ((S6+255)/256)

static __device__ __forceinline__ void transpose_body(
    const float* __restrict__ in, unsigned short* __restrict__ Xt,
    int C, int CinPad, int T, int Trow,
    int bx, int by, int bz, float s[32][33])
{
    int ci0 = by * 32, tr0 = bx * 32;
    int tx = threadIdx.x & 31, ty = threadIdx.x >> 5;
#pragma unroll
    for (int i = 0; i < 4; i++) {
        int c = ci0 + ty + 8 * i;
        int t_in = tr0 + tx - 1;
        float v = (c < C && t_in >= 0 && t_in < T)
                    ? in[((size_t)bz * C + c) * T + t_in] : 0.f;
        s[ty + 8 * i][tx] = v;
    }
    __syncthreads();
#pragma unroll
    for (int i = 0; i < 4; i++) {
        int tr = tr0 + ty + 8 * i;
        if (tr < Trow)
            Xt[((size_t)bz * Trow + tr) * CinPad + ci0 + tx] = f2bf(s[tx][ty + 8 * i]);
    }
}

__global__ __launch_bounds__(256) void prep_all(
    const float* __restrict__ keys, const float* __restrict__ queries,
    const float* __restrict__ kw1, const float* __restrict__ kw2,
    const float* __restrict__ qw1, const float* __restrict__ qw2,
    const float* __restrict__ qw3,
    unsigned short* __restrict__ Xk, unsigned short* __restrict__ Xq,
    unsigned short* __restrict__ Wk1, unsigned short* __restrict__ Wk2,
    unsigned short* __restrict__ Wq1, unsigned short* __restrict__ Wq2,
    unsigned short* __restrict__ Wq3)
{
    __shared__ float s[32][33];
    int bxg = blockIdx.x;
    if (bxg < NKB) {
        int x = bxg % 13, y = (bxg / 13) & 15, z = bxg / (13 * 16);
        transpose_body(keys, Xk, 512, 512, 400, 404, x, y, z, s);
    } else if (bxg < NKB + NQB) {
        int b2 = bxg - NKB;
        int x = b2 % 51, y = (b2 / 51) % 3, z = b2 / 153;
        transpose_body(queries, Xq, 80, 96, 1600, 1604, x, y, z, s);
    } else {
        int idx = (bxg - NKB - NQB) * 256 + threadIdx.x;
        if (idx < S0)      fill_w(kw1, Wk1, idx,       1024, 512, 3, 1024, 512);
        else if (idx < S1) fill_w(kw2, Wk2, idx - S0,  80, 1024, 1, 128, 1024);
        else if (idx < S2) fill_w(qw1, Wq1, idx - S1,  160, 80, 3, 256, 96);
        else if (idx < S3) fill_w(qw2, Wq2, idx - S2,  80, 160, 1, 128, 160);
        else if (idx < S4) fill_w(qw3, Wq3, idx - S3,  80, 80, 1, 128, 96);
        else if (idx < S5) Xk[(size_t)12928 * 512 + (idx - S4)] = 0;
        else if (idx < S6) Xq[(size_t)51328 * 96  + (idx - S5)] = 0;
    }
}

// ---------------- kernel 2: both 3-tap convs (128x256, counted vmcnt) -------
__global__ __launch_bounds__(512) void conv1_both(
    const unsigned short* __restrict__ Wk1, const unsigned short* __restrict__ Xk,
    const float* __restrict__ kb1, unsigned short* __restrict__ K1t,
    const unsigned short* __restrict__ Wq1, const unsigned short* __restrict__ Xq,
    const float* __restrict__ qb1, unsigned short* __restrict__ Q1t)
{
    constexpr int TRW = 136;
    __shared__ unsigned short lds[24576];

    const int tid  = threadIdx.x;
    const int lane = tid & 63;
    const int wid  = tid >> 6;
    const int wm   = wid >> 2;
    const int wn   = wid & 3;

    // XCD-bijective swizzle over combined grid (810)
    const int nwg = gridDim.x;
    const int q8  = nwg >> 3, r8 = nwg & 7;
    const int xcd = blockIdx.x & 7, ix = blockIdx.x >> 3;
    int wgid = (xcd < r8 ? xcd * (q8 + 1) : r8 * (q8 + 1) + (xcd - r8) * q8) + ix;

    const unsigned short* Wbf; const unsigned short* Xt;
    const float* bias; unsigned short* out;
    int CinPad, CoutAlloc, Cout, Trow, Tout, OutStride, nCo, Nvalid;
    if (wgid < 408) {
        Wbf = Wk1; Xt = Xk; bias = kb1; out = K1t;
        CinPad = 512; CoutAlloc = 1024; Cout = 1024; Trow = 404; Tout = 400;
        OutStride = 1024; nCo = 8; Nvalid = 12928;
    } else {
        wgid -= 408;
        Wbf = Wq1; Xt = Xq; bias = qb1; out = Q1t;
        CinPad = 96; CoutAlloc = 256; Cout = 160; Trow = 1604; Tout = 1600;
        OutStride = 160; nCo = 2; Nvalid = 51328;
    }
    const int co0 = (wgid % nCo) * 128;
    const int n0  = (wgid / nCo) * 256;

    const int lr = lane >> 2;
    const int lc = (lane & 3) * 8;
    const int fr = lane & 15;
    const int ko = (lane >> 4) * 8;

    const int nKc   = CinPad >> 5;
    const int nIter = 3 * nKc;

    f32x4 a4[4][4] = {};

    int scc = 0, sd = 0;
#define STAGE(B)                                                                  \
    {                                                                             \
        const unsigned short* asrc =                                              \
            Wbf + ((size_t)sd * CoutAlloc + co0 + wid * 16 + lr) * CinPad + scc * 32 + lc; \
        const unsigned short* bsrc =                                              \
            Xt + ((size_t)(n0 + sd) + wid * 32 + lr) * CinPad + scc * 32 + lc;    \
        unsigned short* Ab = lds + (B) * 12288;                                   \
        GLOAD16(asrc, &Ab[wid * 512]);                                            \
        GLOAD16(bsrc, &Ab[4096 + wid * 1024]);                                    \
        GLOAD16(bsrc + (size_t)16 * CinPad, &Ab[4096 + wid * 1024 + 512]);        \
        scc++; if (scc == nKc) { scc = 0; sd++; }                                 \
    }

#define COMPUTE(B)                                                                \
    {                                                                             \
        const unsigned short* Ab = lds + (B) * 12288;                             \
        const unsigned short* Bb = Ab + 4096;                                     \
        bf16x8 af[4], bfr[4];                                                     \
        _Pragma("unroll")                                                         \
        for (int mi = 0; mi < 4; mi++)                                            \
            af[mi] = *(const bf16x8*)&Ab[(wm * 64 + mi * 16 + fr) * 32 + ko];     \
        _Pragma("unroll")                                                         \
        for (int ni = 0; ni < 4; ni++)                                            \
            bfr[ni] = *(const bf16x8*)&Bb[(wn * 64 + ni * 16 + fr) * 32 + ko];    \
        _Pragma("unroll")                                                         \
        for (int mi = 0; mi < 4; mi++)                                            \
            _Pragma("unroll")                                                     \
            for (int ni = 0; ni < 4; ni++)                                        \
                a4[mi][ni] = __builtin_amdgcn_mfma_f32_16x16x32_bf16(             \
                    af[mi], bfr[ni], a4[mi][ni], 0, 0, 0);                        \
    }

    STAGE(0);
    STAGE(1);

    for (int t = 0; t < nIter; t++) {
        if (t < nIter - 1)
            asm volatile("s_waitcnt vmcnt(3)" ::: "memory");
        else
            asm volatile("s_waitcnt vmcnt(0)" ::: "memory");
        __builtin_amdgcn_s_barrier();
        COMPUTE(t & 1);
        __builtin_amdgcn_sched_barrier(0);
        __builtin_amdgcn_s_barrier();
        if (t + 2 < nIter) STAGE(t & 1);
    }
#undef STAGE
#undef COMPUTE

    __syncthreads();

    int cw = OutStride - co0; if (cw > 128) cw = 128;
#pragma unroll
    for (int p = 0; p < 4; p++) {
        if (wn == p) {
#pragma unroll
            for (int mi = 0; mi < 4; mi++) {
                int col = wm * 64 + mi * 16 + (lane >> 4) * 4;
#pragma unroll
                for (int ni = 0; ni < 4; ni++) {
                    int row = ni * 16 + fr;
                    unsigned short pk[4];
#pragma unroll
                    for (int r = 0; r < 4; r++) {
                        int co = co0 + col + r;
                        float v = 0.f;
                        if (co < Cout) v = fmaxf(a4[mi][ni][r] + bias[co], 0.f);
                        pk[r] = f2bf(v);
                    }
                    *(unsigned long long*)&lds[row * TRW + col] = *(unsigned long long*)pk;
                }
            }
        }
        __syncthreads();
        int row = tid >> 3;
        int c0  = (tid & 7) * 16;
        int n   = n0 + p * 64 + row;
        if (n < Nvalid && c0 < cw) {
            int b = n / Trow;
            int t = n - b * Trow;
            if (t < Tout) {
                unsigned short* dst = out + ((size_t)b * Tout + t) * OutStride + co0 + c0;
                *(bf16x8*)&dst[0] = *(const bf16x8*)&lds[row * TRW + c0];
                *(bf16x8*)&dst[8] = *(const bf16x8*)&lds[row * TRW + c0 + 8];
            }
        }
        __syncthreads();
    }
}

// ---------------- kernel 3: key conv2 (+k2) || q conv2+conv3 ----------------
__global__ __launch_bounds__(256) void conv2_both(
    const unsigned short* __restrict__ Wk2, const unsigned short* __restrict__ K1t,
    const float* __restrict__ kb2, unsigned short* __restrict__ Kt,
    float* __restrict__ k2s,
    const unsigned short* __restrict__ W2, const unsigned short* __restrict__ W3,
    const float* __restrict__ b2, const float* __restrict__ b3,
    const unsigned short* __restrict__ Q1t, unsigned short* __restrict__ Qt)
{
    constexpr int LDW = 40, TRW = 136, X2W = 104;
    __shared__ unsigned short lds[23552];
    unsigned short* Al = lds;
    unsigned short* Bl = lds + 5120;

    const int tid  = threadIdx.x;
    const int lane = tid & 63;
    const int wid  = tid >> 6;
    const int wm   = wid >> 1;
    const int wn   = wid & 1;
    const int r0 = tid >> 2;
    const int r1 = r0 + 64;
    const int q0 = (tid & 3) * 8;
    const int fr = lane & 15;
    const int ko = (lane >> 4) * 8;

    if (blockIdx.x < 100) {
        // ---- key conv2: 128co x 128n, K=1024, reg-staged, + k2 ----
        const int n0 = blockIdx.x * 128;
        f32x4 acc[4][4] = {};

        bf16x8 ra0 = *(const bf16x8*)&Wk2[(size_t)r0 * 1024 + q0];
        bf16x8 ra1 = *(const bf16x8*)&Wk2[(size_t)r1 * 1024 + q0];
        bf16x8 rb0 = *(const bf16x8*)&K1t[(size_t)(n0 + r0) * 1024 + q0];
        bf16x8 rb1 = *(const bf16x8*)&K1t[(size_t)(n0 + r1) * 1024 + q0];

        for (int kk = 0; kk < 32; kk++) {
            __syncthreads();
            *(bf16x8*)&Al[r0 * LDW + q0] = ra0;
            *(bf16x8*)&Al[r1 * LDW + q0] = ra1;
            *(bf16x8*)&Bl[r0 * LDW + q0] = rb0;
            *(bf16x8*)&Bl[r1 * LDW + q0] = rb1;
            __syncthreads();

            if (kk < 31) {
                int ci0 = (kk + 1) * 32;
                ra0 = *(const bf16x8*)&Wk2[(size_t)r0 * 1024 + ci0 + q0];
                ra1 = *(const bf16x8*)&Wk2[(size_t)r1 * 1024 + ci0 + q0];
                rb0 = *(const bf16x8*)&K1t[(size_t)(n0 + r0) * 1024 + ci0 + q0];
                rb1 = *(const bf16x8*)&K1t[(size_t)(n0 + r1) * 1024 + ci0 + q0];
            }

            bf16x8 af[4], bfr[4];
#pragma unroll
            for (int mi = 0; mi < 4; mi++)
                af[mi] = *(const bf16x8*)&Al[(wm * 64 + mi * 16 + fr) * LDW + ko];
#pragma unroll
            for (int ni = 0; ni < 4; ni++)
                bfr[ni] = *(const bf16x8*)&Bl[(wn * 64 + ni * 16 + fr) * LDW + ko];
#pragma unroll
            for (int mi = 0; mi < 4; mi++)
#pragma unroll
                for (int ni = 0; ni < 4; ni++)
                    acc[mi][ni] = __builtin_amdgcn_mfma_f32_16x16x32_bf16(
                        af[mi], bfr[ni], acc[mi][ni], 0, 0, 0);
        }

#pragma unroll
        for (int p = 0; p < 2; p++) {
            __syncthreads();
            if (wn == p) {
#pragma unroll
                for (int mi = 0; mi < 4; mi++) {
                    int col = wm * 64 + mi * 16 + (lane >> 4) * 4;
#pragma unroll
                    for (int ni = 0; ni < 4; ni++) {
                        int row = ni * 16 + fr;
                        unsigned short pk[4];
#pragma unroll
                        for (int r = 0; r < 4; r++) {
                            int co = col + r;
                            float v = 0.f;
                            if (co < 80) v = acc[mi][ni][r] + kb2[co];
                            pk[r] = f2bf(v);
                        }
                        *(unsigned long long*)&lds[row * TRW + col] = *(unsigned long long*)pk;
                    }
                }
            }
            __syncthreads();
            int rr = tid >> 2;
            int c0 = (tid & 3) * 32;
            int n  = n0 + p * 64 + rr;
            unsigned short* dst = Kt + (size_t)n * 96;
            float s = 0.f;
#pragma unroll
            for (int c = c0; c < c0 + 32; c += 8) {
                if (c < 96) {
                    bf16x8 v = *(const bf16x8*)&lds[rr * TRW + c];
                    *(bf16x8*)&dst[c] = v;
#pragma unroll
                    for (int e = 0; e < 8; e++) {
                        float f = bf2f((unsigned short)v[e]);
                        s = fmaf(f, f, s);
                    }
                }
            }
            s += __shfl_xor(s, 1);
            s += __shfl_xor(s, 2);
            if ((tid & 3) == 0) k2s[n] = s;
        }
    } else {
        // ---- q conv2 + conv3 fused ----
        unsigned short* X2 = lds + 10240;
        const int n0 = (blockIdx.x - 100) * 128;

        f32x4 acc[4][4] = {};

        bf16x8 ra0 = *(const bf16x8*)&W2[(size_t)r0 * 160 + q0];
        bf16x8 ra1 = *(const bf16x8*)&W2[(size_t)r1 * 160 + q0];
        bf16x8 rb0 = *(const bf16x8*)&Q1t[(size_t)(n0 + r0) * 160 + q0];
        bf16x8 rb1 = *(const bf16x8*)&Q1t[(size_t)(n0 + r1) * 160 + q0];

        for (int kk = 0; kk < 5; kk++) {
            __syncthreads();
            *(bf16x8*)&Al[r0 * LDW + q0] = ra0;
            *(bf16x8*)&Al[r1 * LDW + q0] = ra1;
            *(bf16x8*)&Bl[r0 * LDW + q0] = rb0;
            *(bf16x8*)&Bl[r1 * LDW + q0] = rb1;
            __syncthreads();

            if (kk < 4) {
                int ci0 = (kk + 1) * 32;
                ra0 = *(const bf16x8*)&W2[(size_t)r0 * 160 + ci0 + q0];
                ra1 = *(const bf16x8*)&W2[(size_t)r1 * 160 + ci0 + q0];
                rb0 = *(const bf16x8*)&Q1t[(size_t)(n0 + r0) * 160 + ci0 + q0];
                rb1 = *(const bf16x8*)&Q1t[(size_t)(n0 + r1) * 160 + ci0 + q0];
            }

            bf16x8 af[4], bfr[4];
#pragma unroll
            for (int mi = 0; mi < 4; mi++)
                af[mi] = *(const bf16x8*)&Al[(wm * 64 + mi * 16 + fr) * LDW + ko];
#pragma unroll
            for (int ni = 0; ni < 4; ni++)
                bfr[ni] = *(const bf16x8*)&Bl[(wn * 64 + ni * 16 + fr) * LDW + ko];
#pragma unroll
            for (int mi = 0; mi < 4; mi++)
#pragma unroll
                for (int ni = 0; ni < 4; ni++)
                    acc[mi][ni] = __builtin_amdgcn_mfma_f32_16x16x32_bf16(
                        af[mi], bfr[ni], acc[mi][ni], 0, 0, 0);
        }

#pragma unroll
        for (int mi = 0; mi < 4; mi++) {
            int col = wm * 64 + mi * 16 + (lane >> 4) * 4;
            if (col >= 96) continue;
#pragma unroll
            for (int ni = 0; ni < 4; ni++) {
                int row = wn * 64 + ni * 16 + fr;
                unsigned short pk[4];
#pragma unroll
                for (int r = 0; r < 4; r++) {
                    int co = col + r;
                    float v = 0.f;
                    if (co < 80) v = fmaxf(acc[mi][ni][r] + b2[co], 0.f);
                    pk[r] = f2bf(v);
                }
                *(unsigned long long*)&X2[row * X2W + col] = *(unsigned long long*)pk;
            }
        }

#pragma unroll
        for (int mi = 0; mi < 4; mi++)
#pragma unroll
            for (int ni = 0; ni < 4; ni++)
                acc[mi][ni] = (f32x4){0.f, 0.f, 0.f, 0.f};

        ra0 = *(const bf16x8*)&W3[(size_t)r0 * 96 + q0];
        ra1 = *(const bf16x8*)&W3[(size_t)r1 * 96 + q0];

        for (int kk = 0; kk < 3; kk++) {
            __syncthreads();
            *(bf16x8*)&Al[r0 * LDW + q0] = ra0;
            *(bf16x8*)&Al[r1 * LDW + q0] = ra1;
            __syncthreads();

            if (kk < 2) {
                int ci0 = (kk + 1) * 32;
                ra0 = *(const bf16x8*)&W3[(size_t)r0 * 96 + ci0 + q0];
                ra1 = *(const bf16x8*)&W3[(size_t)r1 * 96 + ci0 + q0];
            }

            bf16x8 af[4], bfr[4];
#pragma unroll
            for (int mi = 0; mi < 4; mi++)
                af[mi] = *(const bf16x8*)&Al[(wm * 64 + mi * 16 + fr) * LDW + ko];
#pragma unroll
            for (int ni = 0; ni < 4; ni++)
                bfr[ni] = *(const bf16x8*)&X2[(wn * 64 + ni * 16 + fr) * X2W + kk * 32 + ko];
#pragma unroll
            for (int mi = 0; mi < 4; mi++)
#pragma unroll
                for (int ni = 0; ni < 4; ni++)
                    acc[mi][ni] = __builtin_amdgcn_mfma_f32_16x16x32_bf16(
                        af[mi], bfr[ni], acc[mi][ni], 0, 0, 0);
        }

#pragma unroll
        for (int p = 0; p < 2; p++) {
            __syncthreads();
            if (wn == p) {
#pragma unroll
                for (int mi = 0; mi < 4; mi++) {
                    int col = wm * 64 + mi * 16 + (lane >> 4) * 4;
#pragma unroll
                    for (int ni = 0; ni < 4; ni++) {
                        int row = ni * 16 + fr;
                        unsigned short pk[4];
#pragma unroll
                        for (int r = 0; r < 4; r++) {
                            int co = col + r;
                            float v = 0.f;
                            if (co < 80) v = acc[mi][ni][r] + b3[co];
                            pk[r] = f2bf(v);
                        }
                        *(unsigned long long*)&lds[row * TRW + col] = *(unsigned long long*)pk;
                    }
                }
            }
            __syncthreads();
            int rr = tid >> 2;
            int c0 = (tid & 3) * 32;
            int n  = n0 + p * 64 + rr;
            unsigned short* dst = Qt + (size_t)n * 96;
#pragma unroll
            for (int c = c0; c < c0 + 32; c += 8)
                if (c < 96)
                    *(bf16x8*)&dst[c] = *(const bf16x8*)&lds[rr * TRW + c];
        }
    }
}

// ---------------- kernel 4: fused MFMA-QK + softmax/logprob ----------------
#define NS 7
#define SCW 404
__global__ __launch_bounds__(512) void attn_v2(
    const unsigned short* __restrict__ Kt,   // [32*400][96] bf16
    const unsigned short* __restrict__ Qt,   // [32*1600][96] bf16
    const float* __restrict__ k2s,           // [32*400]
    const float* __restrict__ prior, const int* __restrict__ mask,
    float* __restrict__ out_attn, float* __restrict__ out_lp)
{
    const int T1 = 1600, T2 = 400;
    __shared__ float Sc[32 * SCW];

    const int tid  = threadIdx.x;
    const int lane = tid & 63;
    const int wid  = tid >> 6;
    const int b    = blockIdx.y;
    const int t0   = blockIdx.x * 32;
    const int fr   = lane & 15;
    const int ko   = (lane >> 4) * 8;

    bf16x8 qf[2][3];
#pragma unroll
    for (int ts = 0; ts < 2; ts++)
#pragma unroll
        for (int kk = 0; kk < 3; kk++)
            qf[ts][kk] = *(const bf16x8*)&Qt[((size_t)b * T1 + t0 + ts * 16 + fr) * 96 + kk * 32 + ko];

    for (int st = wid; st < 25; st += 8) {
        f32x4 acc0 = {}, acc1 = {};
#pragma unroll
        for (int kk = 0; kk < 3; kk++) {
            bf16x8 kf = *(const bf16x8*)&Kt[((size_t)b * T2 + st * 16 + fr) * 96 + kk * 32 + ko];
            acc0 = __builtin_amdgcn_mfma_f32_16x16x32_bf16(kf, qf[0][kk], acc0, 0, 0, 0);
            acc1 = __builtin_amdgcn_mfma_f32_16x16x32_bf16(kf, qf[1][kk], acc1, 0, 0, 0);
        }
        int sbase = st * 16 + (lane >> 4) * 4;
        float4 kv = *(const float4*)&k2s[b * T2 + sbase];
        float4 w0, w1;
        w0.x = fmaf(1e-3f, acc0[0], -5e-4f * kv.x);
        w0.y = fmaf(1e-3f, acc0[1], -5e-4f * kv.y);
        w0.z = fmaf(1e-3f, acc0[2], -5e-4f * kv.z);
        w0.w = fmaf(1e-3f, acc0[3], -5e-4f * kv.w);
        w1.x = fmaf(1e-3f, acc1[0], -5e-4f * kv.x);
        w1.y = fmaf(1e-3f, acc1[1], -5e-4f * kv.y);
        w1.z = fmaf(1e-3f, acc1[2], -5e-4f * kv.z);
        w1.w = fmaf(1e-3f, acc1[3], -5e-4f * kv.w);
        *(float4*)&Sc[fr * SCW + sbase]        = w0;
        *(float4*)&Sc[(16 + fr) * SCW + sbase] = w1;
    }

    int mk[NS];
#pragma unroll
    for (int j = 0; j < NS; j++) {
        int s = lane + 64 * j;
        mk[j] = (s < T2) ? mask[b * T2 + s] : 1;
    }

    __syncthreads();

    for (int r = 0; r < 4; r++) {
        int tloc = wid * 4 + r;
        int t = t0 + tloc;

        float scr[NS];
        float m = -INFINITY;
#pragma unroll
        for (int j = 0; j < NS; j++) {
            int s = lane + 64 * j;
            if (s < T2) {
                scr[j] = Sc[tloc * SCW + s];
                m = fmaxf(m, scr[j]);
            } else {
                scr[j] = -INFINITY;
            }
        }
#pragma unroll
        for (int o = 32; o >= 1; o >>= 1) m = fmaxf(m, __shfl_xor(m, o));
        float sum = 0.f;
#pragma unroll
        for (int j = 0; j < NS; j++) {
            int s = lane + 64 * j;
            if (s < T2) sum += __expf(scr[j] - m);
        }
#pragma unroll
        for (int o = 32; o >= 1; o >>= 1) sum += __shfl_xor(sum, o);
        float lse = m + __logf(sum);

        const float* pr = prior + ((size_t)b * T1 + t) * T2;
        float* lpout = out_lp + ((size_t)b * T1 + t) * T2;
        float* atout = out_attn + ((size_t)b * T1 + t) * T2;

        float val[NS];
        float m2 = -INFINITY;
#pragma unroll
        for (int j = 0; j < NS; j++) {
            int s = lane + 64 * j;
            if (s < T2) {
                float lp = scr[j] - lse + __logf(pr[s] + 1e-8f);
                lpout[s] = lp;
                val[j] = mk[j] ? -INFINITY : lp;
                m2 = fmaxf(m2, val[j]);
            } else {
                val[j] = -INFINITY;
            }
        }
#pragma unroll
        for (int o = 32; o >= 1; o >>= 1) m2 = fmaxf(m2, __shfl_xor(m2, o));
        float ex[NS];
        float sum2 = 0.f;
#pragma unroll
        for (int j = 0; j < NS; j++) { ex[j] = __expf(val[j] - m2); sum2 += ex[j]; }
#pragma unroll
        for (int o = 32; o >= 1; o >>= 1) sum2 += __shfl_xor(sum2, o);
        float inv = 1.f / sum2;
#pragma unroll
        for (int j = 0; j < NS; j++) {
            int s = lane + 64 * j;
            if (s < T2) atout[s] = ex[j] * inv;
        }
    }
}

// ---------------------------------------------------------------------------
extern "C" void kernel_launch(void* const* d_in, const int* in_sizes, int n_in,
                              void* d_out, int out_size, void* d_ws, size_t ws_size,
                              hipStream_t stream)
{
    (void)in_sizes; (void)n_in; (void)out_size; (void)ws_size;

    const float* queries = (const float*)d_in[0];
    const float* keys    = (const float*)d_in[1];
    const float* prior   = (const float*)d_in[2];
    const int*   mask    = (const int*)d_in[3];
    const float* kw1     = (const float*)d_in[4];
    const float* kb1     = (const float*)d_in[5];
    const float* kw2     = (const float*)d_in[6];
    const float* kb2     = (const float*)d_in[7];
    const float* qw1     = (const float*)d_in[8];
    const float* qb1     = (const float*)d_in[9];
    const float* qw2     = (const float*)d_in[10];
    const float* qb2     = (const float*)d_in[11];
    const float* qw3     = (const float*)d_in[12];
    const float* qb3     = (const float*)d_in[13];

    unsigned short* U = (unsigned short*)d_ws;
    unsigned short* K1t = U;                        // [12800][1024]
    unsigned short* Q1t = U;                        // [51200][160] (reuse)
    unsigned short* Xk  = U + 13107200;             // [13058][512]
    unsigned short* Qt  = U + 13107200;             // [51200][96] (reuse after key path)
    unsigned short* Xq  = U + 19792896;             // [51458][96]
    unsigned short* Kt  = U + 24732864;             // [12800][96]
    unsigned short* Wk1 = U + 25961664;             // 3*1024*512
    unsigned short* Wk2 = U + 27534528;             // 128*1024
    unsigned short* Wq1 = U + 27665600;             // 3*256*96
    unsigned short* Wq2 = U + 27739328;             // 128*160
    unsigned short* Wq3 = U + 27759808;             // 128*96
    float*          k2s = (float*)(U + 27772096);   // 12800 f32

    float* out_attn = (float*)d_out;
    float* out_lp   = out_attn + (size_t)32 * 1600 * 400;

    // 1) all prep: both input transposes + all weight converts + tail zeroes
    prep_all<<<NKB + NQB + NFB, dim3(256), 0, stream>>>(
        keys, queries, kw1, kw2, qw1, qw2, qw3,
        Xk, Xq, Wk1, Wk2, Wq1, Wq2, Wq3);

    // 2) both 3-tap convs in one launch (key 408 tiles + q 402 tiles)
    conv1_both<<<810, dim3(512), 0, stream>>>(
        Wk1, Xk, kb1, K1t, Wq1, Xq, qb1, Q1t);

    // 3) key conv2 (+k2) || q conv2+conv3 fused
    conv2_both<<<500, dim3(256), 0, stream>>>(
        Wk2, K1t, kb2, Kt, k2s, Wq2, Wq3, qb2, qb3, Q1t, Qt);

    // 4) fused attention + softmaxes
    attn_v2<<<dim3(50, 32), dim3(512), 0, stream>>>(
        Kt, Qt, k2s, prior, mask, out_attn, out_lp);
}